// Round 16
// baseline (2184.791 us; speedup 1.0000x reference)
//
#include <hip/hip_runtime.h>
#include <hip/hip_bf16.h>
#include <math.h>

#define NEXP 8
#define GNUM 16
#define DH 256

typedef __attribute__((ext_vector_type(8))) short s16x8;
typedef __attribute__((ext_vector_type(4))) float f32x4;
typedef unsigned short u16;
typedef unsigned int u32;

__device__ __forceinline__ float bitsToF(u32 b){ union{u32 u; float f;} c; c.u=b; return c.f; }
__device__ __forceinline__ u16 f2bf(float f){
  union{float f; u32 u;} c; c.f=f;
  u32 r = c.u + 0x7fffu + ((c.u>>16)&1u);
  return (u16)(r>>16);
}

#define GLOAD_LDS16(gp, lp) __builtin_amdgcn_global_load_lds( \
    (const __attribute__((address_space(1))) unsigned int*)(gp), \
    (__attribute__((address_space(3))) unsigned int*)(lp), 16, 0, 0)

// ---------------- CSR build ----------------
__global__ void count_edges_k(const int* __restrict__ ei, const int* __restrict__ batch,
                              int* __restrict__ deg, int* __restrict__ eg, int E){
  __shared__ int leg[GNUM];
  int t = threadIdx.x;
  if (t < GNUM) leg[t] = 0;
  __syncthreads();
  int i = blockIdx.x*blockDim.x + t;
  if (i < E){
    int s = ei[i];
    int d = ei[E + i];
    atomicAdd(&deg[d], 1);
    atomicAdd(&leg[batch[s]], 1);
  }
  __syncthreads();
  if (t < GNUM){ int v = leg[t]; if (v) atomicAdd(&eg[t], v); }
}

__global__ void count_nodes_k(const int* __restrict__ batch, int* __restrict__ ng, int N){
  __shared__ int lng[GNUM];
  int t = threadIdx.x;
  if (t < GNUM) lng[t] = 0;
  __syncthreads();
  int i = blockIdx.x*blockDim.x + t;
  if (i < N) atomicAdd(&lng[batch[i]], 1);
  __syncthreads();
  if (t < GNUM){ int v = lng[t]; if (v) atomicAdd(&ng[t], v); }
}

#define SCAN_T 1024
#define SCAN_CH 32
__global__ __launch_bounds__(1024) void scan_deg_k(const int* __restrict__ deg,
    int* __restrict__ row_ptr, int* __restrict__ cursor, int N){
  __shared__ int part[SCAN_T];
  int t = threadIdx.x;
  int base = t*SCAN_CH;
  int loc[SCAN_CH];
  int s = 0;
  #pragma unroll
  for (int j=0;j<SCAN_CH;j++){
    int i = base+j;
    int v = (i<N)? deg[i] : 0;
    loc[j] = s; s += v;
  }
  part[t] = s;
  __syncthreads();
  for (int off=1; off<SCAN_T; off<<=1){
    int add = (t>=off)? part[t-off] : 0;
    __syncthreads();
    part[t] += add;
    __syncthreads();
  }
  int ex = (t==0)? 0 : part[t-1];
  #pragma unroll
  for (int j=0;j<SCAN_CH;j++){
    int i = base+j;
    if (i<N){ int v = ex + loc[j]; row_ptr[i]=v; cursor[i]=v; }
  }
  if (t == SCAN_T-1) row_ptr[N] = part[SCAN_T-1];
}

__global__ void scatter_edges_k(const int* __restrict__ ei, int* __restrict__ cursor,
                                int* __restrict__ csr_src, int E){
  int i = blockIdx.x*blockDim.x + threadIdx.x;
  if (i>=E) return;
  int s = ei[i];
  int d = ei[E + i];
  int pos = atomicAdd(&cursor[d], 1);
  csr_src[pos] = s;
}

__global__ void size_feats_k(const int* __restrict__ ng, const int* __restrict__ eg,
                             float* __restrict__ sizef){
  int g = threadIdx.x;
  if (g < GNUM){
    sizef[g*2]   = logf(fmaxf((float)ng[g], 1.f));
    sizef[g*2+1] = logf(fmaxf((float)eg[g], 1.f));
  }
}

__global__ void mark_fail_k(float* out){ out[0] = __builtin_nanf(""); }

// ---------------- encoder ----------------
__global__ __launch_bounds__(256) void encoder_k(const float* __restrict__ x,
    const float* __restrict__ W, const float* __restrict__ b,
    float* __restrict__ hf, u16* __restrict__ bh, int N){
  int n = blockIdx.x; if (n>=N) return;
  int f = threadIdx.x;
  float acc = b[f];
  #pragma unroll
  for (int k=0;k<6;k++) acc += x[n*6+k]*W[k*DH+f];
  acc = fmaxf(acc, 0.f);
  hf[(size_t)n*DH+f] = acc;
  bh[(size_t)n*DH+f] = f2bf(acc);
}

// ---------------- weight convert ----------------
__global__ __launch_bounds__(256) void convw_k(const float* __restrict__ Wrel,
    const float* __restrict__ Wroot, u16* __restrict__ WT){
  __shared__ float tile[64][65];
  int tx = threadIdx.x;
  int ty = threadIdx.y;
  int kt = blockIdx.x & 3, ct = blockIdx.x >> 2;
  int srcRoot = blockIdx.y;
  int le = blockIdx.z;
  const float* src = (srcRoot ? Wroot : Wrel) + (size_t)le*65536;
  #pragma unroll
  for (int i=0;i<16;i++){
    int kl = ty + i*4;
    tile[kl][tx] = src[(size_t)(kt*64 + kl)*256 + ct*64 + tx];
  }
  __syncthreads();
  u16* dst = WT + (size_t)le*131072 + (srcRoot ? 256 : 0) + kt*64;
  #pragma unroll
  for (int i=0;i<16;i++){
    int cl = ty + i*4;
    dst[(size_t)(ct*64 + cl)*512 + tx] = f2bf(tile[tx][cl]);
  }
}

// ---------------- router layer 1 ----------------
#define R1N 32
__global__ __launch_bounds__(256) void router1_k(
    const float* __restrict__ hf, const float* __restrict__ sizef,
    const int* __restrict__ batch,
    const float* __restrict__ W1, const float* __restrict__ b1,
    float* __restrict__ rh, int N)
{
  __shared__ float xin[R1N][264];
  int t = threadIdx.x;
  int lane = t & 63, w = t >> 6;
  int n0 = blockIdx.x * R1N;
  #pragma unroll
  for (int i=0;i<R1N;i++){
    int n = n0 + i;
    xin[i][t] = (n<N) ? hf[(size_t)n*DH + t] : 0.f;
  }
  if (t < R1N){
    int n = n0 + t;
    int g = (n<N) ? (int)batch[n] : 0;
    xin[t][256] = sizef[g*2];
    xin[t][257] = sizef[g*2+1];
    xin[t][258] = 0.f; xin[t][259] = 0.f;
    xin[t][260] = 0.f; xin[t][261] = 0.f; xin[t][262] = 0.f; xin[t][263] = 0.f;
  }
  __syncthreads();

  int wn = w*8;
  float bb[4];
  #pragma unroll
  for (int c=0;c<4;c++) bb[c] = b1[lane + c*64];
  float acc[8][4];
  #pragma unroll
  for (int i=0;i<8;i++)
    #pragma unroll
    for (int c=0;c<4;c++) acc[i][c] = bb[c];

  #pragma unroll 2
  for (int k4=0; k4<256; k4+=4){
    float w4[4][4];
    #pragma unroll
    for (int j=0;j<4;j++)
      #pragma unroll
      for (int c=0;c<4;c++)
        w4[j][c] = W1[(size_t)(k4+j)*DH + lane + c*64];
    #pragma unroll
    for (int i=0;i<8;i++){
      f32x4 xv = *(const f32x4*)&xin[wn+i][k4];
      #pragma unroll
      for (int j=0;j<4;j++)
        #pragma unroll
        for (int c=0;c<4;c++)
          acc[i][c] += xv[j]*w4[j][c];
    }
  }
  float w256[4], w257[4];
  #pragma unroll
  for (int c=0;c<4;c++){
    w256[c] = W1[(size_t)256*DH + lane + c*64];
    w257[c] = W1[(size_t)257*DH + lane + c*64];
  }
  #pragma unroll
  for (int i=0;i<8;i++){
    float s0 = xin[wn+i][256], s1 = xin[wn+i][257];
    #pragma unroll
    for (int c=0;c<4;c++) acc[i][c] += s0*w256[c] + s1*w257[c];
  }
  #pragma unroll
  for (int i=0;i<8;i++){
    int n = n0 + wn + i;
    if (n < N){
      #pragma unroll
      for (int c=0;c<4;c++)
        rh[(size_t)n*DH + lane + c*64] = fmaxf(acc[i][c], 0.f);
    }
  }
}

// ---------------- router layer 2 + softmax + top2 ----------------
__global__ __launch_bounds__(256) void router2_k(
    const float* __restrict__ rh, const float* __restrict__ W2,
    const float* __restrict__ b2,
    int* __restrict__ ridx, float* __restrict__ rval, int N)
{
  __shared__ float w2s[NEXP][260];
  int t = threadIdx.x;
  for (int i=t; i<NEXP*DH; i+=256){
    int e = i >> 8, k = i & 255;
    w2s[e][k] = W2[(size_t)k*NEXP + e];
  }
  __syncthreads();
  int lane = t & 63, w = t >> 6;
  int n = blockIdx.x*4 + w;
  if (n >= N) return;
  const float* r = rh + (size_t)n*DH;
  float p[NEXP];
  #pragma unroll
  for (int e=0;e<NEXP;e++) p[e] = 0.f;
  #pragma unroll
  for (int c=0;c<4;c++){
    int k = lane + c*64;
    float rv = r[k];
    #pragma unroll
    for (int e=0;e<NEXP;e++) p[e] += rv * w2s[e][k];
  }
  #pragma unroll
  for (int off=1; off<64; off<<=1){
    #pragma unroll
    for (int e=0;e<NEXP;e++) p[e] += __shfl_xor(p[e], off, 64);
  }
  if (lane == 0){
    float l0[NEXP];
    #pragma unroll
    for (int e=0;e<NEXP;e++) l0[e] = p[e] + b2[e];
    float m = l0[0];
    #pragma unroll
    for (int e=1;e<NEXP;e++) m = fmaxf(m, l0[e]);
    float ex[NEXP];
    #pragma unroll
    for (int e=0;e<NEXP;e++) ex[e] = expf(l0[e]-m);
    int e0=0; float b0v=ex[0];
    #pragma unroll
    for (int e=1;e<NEXP;e++) if (ex[e]>b0v){b0v=ex[e]; e0=e;}
    int e1=(e0==0)?1:0; float b1v=ex[e1];
    #pragma unroll
    for (int e=0;e<NEXP;e++) if (e!=e0 && ex[e]>b1v){b1v=ex[e]; e1=e;}
    float sv = b0v + b1v;
    rval[n*2]   = b0v/sv;
    rval[n*2+1] = b1v/sv;
    ridx[n*2]   = e0;
    ridx[n*2+1] = e1;
  }
}

// ---------------- routing scatter (hierarchical) ----------------
__global__ __launch_bounds__(256) void rsort_k(const int* __restrict__ ridx,
    int* __restrict__ cnt, int* __restrict__ plist, int* __restrict__ ppos, int N){
  __shared__ int lcnt[NEXP];
  __shared__ int lbase[NEXP];
  int t = threadIdx.x;
  int n = blockIdx.x*256 + t;
  if (t < NEXP) lcnt[t] = 0;
  __syncthreads();
  int e0=0, e1=0, o0=0, o1=0;
  if (n < N){
    e0 = ridx[n*2];
    e1 = ridx[n*2+1];
    o0 = atomicAdd(&lcnt[e0], 1);
    o1 = atomicAdd(&lcnt[e1], 1);
  }
  __syncthreads();
  if (t < NEXP) lbase[t] = atomicAdd(&cnt[t], lcnt[t]);
  __syncthreads();
  if (n < N){
    int p0 = lbase[e0] + o0;
    int p1 = lbase[e1] + o1;
    plist[(size_t)e0*N + p0] = n;
    plist[(size_t)e1*N + p1] = n;
    ppos[n*2]   = p0;
    ppos[n*2+1] = p1;
  }
}

// ---------------- aggregation device body (full-row, for agg0) ------------
__device__ __forceinline__ void agg_row(const u16* __restrict__ H,
    u16* __restrict__ Arow, const int* __restrict__ row_ptr,
    const int* __restrict__ csr_src, int node, int lane){
  int beg = row_ptr[node], end = row_ptr[node+1];
  float a0=0.f,a1=0.f,a2=0.f,a3=0.f;
  const u16* Hl = H + (lane<<2);
  int i = beg;
  for (; i+8<=end; i+=8){
    int sarr[8];
    #pragma unroll
    for (int u=0;u<8;u++) sarr[u] = csr_src[i+u];
    #pragma unroll
    for (int u=0;u<8;u++){
      uint2 v = *(const uint2*)(Hl + ((size_t)sarr[u]<<8));
      a0 += bitsToF(v.x<<16);
      a1 += bitsToF(v.x & 0xffff0000u);
      a2 += bitsToF(v.y<<16);
      a3 += bitsToF(v.y & 0xffff0000u);
    }
  }
  for (; i<end; ++i){
    int s = csr_src[i];
    uint2 v = *(const uint2*)(Hl + ((size_t)s<<8));
    a0 += bitsToF(v.x<<16);
    a1 += bitsToF(v.x & 0xffff0000u);
    a2 += bitsToF(v.y<<16);
    a3 += bitsToF(v.y & 0xffff0000u);
  }
  uint2 o;
  o.x = ((u32)f2bf(a1)<<16) | f2bf(a0);
  o.y = ((u32)f2bf(a3)<<16) | f2bf(a2);
  *(uint2*)(Arow + (lane<<2)) = o;
}

// layer-0 shared aggregate (single L2-friendly table)
__global__ __launch_bounds__(256) void agg0_k(const u16* __restrict__ H,
    u16* __restrict__ A, const int* __restrict__ row_ptr,
    const int* __restrict__ csr_src, int N){
  int node = blockIdx.x*4 + (threadIdx.x>>6);
  if (node >= N) return;
  int lane = threadIdx.x & 63;
  agg_row(H, A + ((size_t)node<<8), row_ptr, csr_src, node, lane);
}

// ---------------- column-quartered gathers ----------------
// Per dispatch: cols [qoff, qoff+64) elems = 128B/row. Per-expert working set
// = N*128B = 3.84MB < 4MB XCD L2 (with expert->XCD pinning -> L2-resident).
// Lane map: e4 = lane>>4 (edge subgroup, 4 edges/iter), c16 = lane&15
// (8B col-pair). Final reduce across e4 via shfl_xor(16,32).

// dense layer-1 quarter gather
__global__ __launch_bounds__(256) void agg1q_k(const u16* __restrict__ Hsrc,
    u16* __restrict__ Aout, const int* __restrict__ row_ptr,
    const int* __restrict__ csr_src, int N, int qoff, int ezMask, int ezShift){
  int bid = blockIdx.x;
  int el = bid & ezMask;
  int xb = bid >> ezShift;
  int node = xb*4 + (threadIdx.x>>6);
  if (node >= N) return;
  int lane = threadIdx.x & 63;
  int e4 = lane >> 4, c16 = lane & 15;
  size_t NS = (size_t)N*DH;
  const u16* Hq = Hsrc + (size_t)el*NS + qoff + (c16<<2);
  int beg = row_ptr[node], end = row_ptr[node+1];
  float a0=0.f,a1=0.f,a2=0.f,a3=0.f;
  for (int i = beg; i < end; i += 4){
    int ii = i + e4;
    if (ii < end){
      int s = csr_src[ii];
      uint2 v = *(const uint2*)(Hq + ((size_t)s<<8));
      a0 += bitsToF(v.x<<16);
      a1 += bitsToF(v.x & 0xffff0000u);
      a2 += bitsToF(v.y<<16);
      a3 += bitsToF(v.y & 0xffff0000u);
    }
  }
  #pragma unroll
  for (int off=16; off<64; off<<=1){
    a0 += __shfl_xor(a0, off, 64);
    a1 += __shfl_xor(a1, off, 64);
    a2 += __shfl_xor(a2, off, 64);
    a3 += __shfl_xor(a3, off, 64);
  }
  if (e4 == 0){
    uint2 o;
    o.x = ((u32)f2bf(a1)<<16) | f2bf(a0);
    o.y = ((u32)f2bf(a3)<<16) | f2bf(a2);
    *(uint2*)(Aout + (size_t)el*NS + ((size_t)node<<8) + qoff + (c16<<2)) = o;
  }
}

// sparse layer-2 quarter gather + quartered root compaction
__global__ __launch_bounds__(256) void agg2q_k(const u16* __restrict__ Hsrc,
    u16* __restrict__ Aout, u16* __restrict__ Rout,
    const int* __restrict__ row_ptr, const int* __restrict__ csr_src,
    const int* __restrict__ plist, const int* __restrict__ cnt,
    int N, int gBase, int qoff, int ezMask, int ezShift){
  int bid = blockIdx.x;
  int el = bid & ezMask;
  int xb = bid >> ezShift;
  int idx = xb*4 + (threadIdx.x>>6);
  if (idx >= cnt[gBase + el]) return;
  int node = plist[(size_t)(gBase + el)*N + idx];
  int lane = threadIdx.x & 63;
  int e4 = lane >> 4, c16 = lane & 15;
  size_t NS = (size_t)N*DH;
  const u16* Hq = Hsrc + (size_t)el*NS + qoff + (c16<<2);
  int beg = row_ptr[node], end = row_ptr[node+1];
  float a0=0.f,a1=0.f,a2=0.f,a3=0.f;
  for (int i = beg; i < end; i += 4){
    int ii = i + e4;
    if (ii < end){
      int s = csr_src[ii];
      uint2 v = *(const uint2*)(Hq + ((size_t)s<<8));
      a0 += bitsToF(v.x<<16);
      a1 += bitsToF(v.x & 0xffff0000u);
      a2 += bitsToF(v.y<<16);
      a3 += bitsToF(v.y & 0xffff0000u);
    }
  }
  #pragma unroll
  for (int off=16; off<64; off<<=1){
    a0 += __shfl_xor(a0, off, 64);
    a1 += __shfl_xor(a1, off, 64);
    a2 += __shfl_xor(a2, off, 64);
    a3 += __shfl_xor(a3, off, 64);
  }
  if (e4 == 0){
    uint2 rv = *(const uint2*)(Hq + ((size_t)node<<8));
    uint2 o;
    o.x = ((u32)f2bf(a1)<<16) | f2bf(a0);
    o.y = ((u32)f2bf(a3)<<16) | f2bf(a2);
    *(uint2*)(Aout + (size_t)el*NS + ((size_t)idx<<8) + qoff + (c16<<2)) = o;
    *(uint2*)(Rout + (size_t)el*NS + ((size_t)idx<<8) + qoff + (c16<<2)) = rv;
  }
}

// ---------------- dense GEMM, BK=64 (round-13 validated) ----------------
__device__ __forceinline__ void gemm_bk64_body(
    const u16* __restrict__ aBase, const u16* __restrict__ rBase,
    const u16* __restrict__ wBase, const float* __restrict__ be,
    u16* __restrict__ Oe, int N, int relu_flag, u16* As, u16* Bs)
{
  int tid = threadIdx.x;
  int lane = tid & 63, w = tid >> 6;
  int wr = w >> 1, wc = w & 1;
  int m0 = blockIdx.x * 128;
  int n0 = blockIdx.y * 128;

  int lr8 = lane >> 3;
  int p   = (lane & 7) ^ lr8;
  long long asrc[4]; u16* aL[4];
  long long bsrc[4]; u16* bL[4];
  #pragma unroll
  for (int j=0;j<4;j++){
    int c = w*4 + j;
    int arow = m0 + c*8 + lr8; if (arow >= N) arow = N-1;
    asrc[j] = (long long)arow*256 + p*8;
    aL[j] = As + (size_t)c*512;
    int bcol = n0 + c*8 + lr8;
    bsrc[j] = (long long)bcol*512 + p*8;
    bL[j] = Bs + (size_t)c*512;
  }

  f32x4 acc[4][4];
  #pragma unroll
  for (int a=0;a<4;a++)
    #pragma unroll
    for (int b=0;b<4;b++) acc[a][b] = (f32x4){0.f,0.f,0.f,0.f};

  int fr = lane & 15;
  int fkq = lane >> 4;

  #pragma unroll 1
  for (int kk=0; kk<8; ++kk){
    const u16* sA = (kk < 4) ? aBase : rBase;
    int koff = (kk & 3) * 64;
    #pragma unroll
    for (int j=0;j<4;j++){
      GLOAD_LDS16(sA + asrc[j] + koff, aL[j]);
      GLOAD_LDS16(wBase + bsrc[j] + kk*64, bL[j]);
    }
    __syncthreads();
    #pragma unroll
    for (int kin=0; kin<2; ++kin){
      unsigned fb = (unsigned)(fkq*16 + kin*64);
      s16x8 af[4], bf[4];
      #pragma unroll
      for (int mi=0;mi<4;mi++){
        int row = wr*64 + mi*16 + fr;
        unsigned byte = ((unsigned)row << 7) + (fb ^ (((unsigned)(row & 7)) << 4));
        af[mi] = *(const s16x8*)((const char*)As + byte);
      }
      #pragma unroll
      for (int ni=0;ni<4;ni++){
        int col = wc*64 + ni*16 + fr;
        unsigned byte = ((unsigned)col << 7) + (fb ^ (((unsigned)(col & 7)) << 4));
        bf[ni] = *(const s16x8*)((const char*)Bs + byte);
      }
      #pragma unroll
      for (int mi=0;mi<4;mi++)
        #pragma unroll
        for (int ni=0;ni<4;ni++)
          acc[mi][ni] = __builtin_amdgcn_mfma_f32_16x16x32_bf16(af[mi], bf[ni], acc[mi][ni], 0, 0, 0);
    }
    __syncthreads();
  }

  int fq = lane >> 4;
  #pragma unroll
  for (int ni=0;ni<4;ni++){
    int col = n0 + wc*64 + ni*16 + fr;
    float bv = be[col];
    #pragma unroll
    for (int mi=0;mi<4;mi++){
      int rowb = m0 + wr*64 + mi*16 + fq*4;
      f32x4 v = acc[mi][ni];
      #pragma unroll
      for (int j=0;j<4;j++){
        int row = rowb + j;
        if (row < N){
          float o = v[j] + bv;
          if (relu_flag) o = fmaxf(o, 0.f);
          Oe[(size_t)row*DH + col] = f2bf(o);
        }
      }
    }
  }
}

__global__ __launch_bounds__(256,2) void gemm0g_k(
    const u16* __restrict__ A0, const u16* __restrict__ bh,
    const u16* __restrict__ WT, const float* __restrict__ bias,
    u16* __restrict__ Hout, int N){
  __shared__ u16 As[128*64];
  __shared__ u16 Bs[128*64];
  int el = blockIdx.z;
  gemm_bk64_body(A0, bh, WT + (size_t)el*(256*512), bias + el*256,
                 Hout + (size_t)el*((size_t)N*DH), N, 1, As, Bs);
}
__global__ __launch_bounds__(256,2) void gemm1g_k(
    const u16* __restrict__ Aagg, const u16* __restrict__ Hroot,
    const u16* __restrict__ WT, const float* __restrict__ bias,
    u16* __restrict__ Hout, int N){
  __shared__ u16 As[128*64];
  __shared__ u16 Bs[128*64];
  int el = blockIdx.z;
  size_t NS = (size_t)N*DH;
  gemm_bk64_body(Aagg + (size_t)el*NS, Hroot + (size_t)el*NS,
                 WT + (size_t)el*(256*512), bias + el*256,
                 Hout + (size_t)el*NS, N, 1, As, Bs);
}

// sparse layer-2 GEMM (round-10/13 validated BK=32 body)
__global__ __launch_bounds__(256,2) void gemm2sg_k(
    const u16* __restrict__ Aagg, const u16* __restrict__ Rc,
    const u16* __restrict__ WT, const float* __restrict__ bias,
    u16* __restrict__ Hout, const int* __restrict__ cnte, int N, int gBase)
{
  __shared__ u16 As[128*32];
  __shared__ u16 Bs[128*32];
  int el = blockIdx.z;
  int cnt = cnte[gBase + el];
  int m0 = blockIdx.x * 128;
  if (m0 >= cnt) return;
  size_t NS = (size_t)N*DH;
  const u16* aBase = Aagg + (size_t)el*NS;
  const u16* rBase = Rc + (size_t)el*NS;
  const u16* wBase = WT + (size_t)el*(256*512);
  const float* be  = bias + el*256;
  u16* Oe = Hout + (size_t)el*NS;

  int tid = threadIdx.x;
  int lane = tid & 63, w = tid >> 6;
  int wr = w >> 1, wc = w & 1;
  int n0 = blockIdx.y * 128;

  int lrow = lane >> 2;
  int q8   = (((lane & 3) ^ ((lane >> 3) & 3))) * 8;
  int r0 = w*16 + lrow;
  int r1 = (w+4)*16 + lrow;
  int ai0 = m0 + r0; if (ai0 >= cnt) ai0 = cnt-1;
  int ai1 = m0 + r1; if (ai1 >= cnt) ai1 = cnt-1;
  long long aoff0 = (long long)ai0*256 + q8;
  long long aoff1 = (long long)ai1*256 + q8;
  long long boff0 = (long long)(n0 + r0)*512 + q8;
  long long boff1 = (long long)(n0 + r1)*512 + q8;
  u16* aL0 = As + (size_t)w*512;
  u16* aL1 = As + (size_t)(w+4)*512;
  u16* bL0 = Bs + (size_t)w*512;
  u16* bL1 = Bs + (size_t)(w+4)*512;

  f32x4 acc[4][4];
  #pragma unroll
  for (int a=0;a<4;a++)
    #pragma unroll
    for (int b=0;b<4;b++) acc[a][b] = (f32x4){0.f,0.f,0.f,0.f};

  int fr = lane & 15;
  int fk = (((lane >> 4) ^ ((fr >> 1) & 3))) * 8;
  const u16* aRead = As + (size_t)(wr*64 + fr)*32 + fk;
  const u16* bRead = Bs + (size_t)(wc*64 + fr)*32 + fk;

  #pragma unroll 1
  for (int half=0; half<2; ++half){
    const u16* sA = half ? rBase : aBase;
    #pragma unroll 1
    for (int kk=0; kk<8; ++kk){
      int kin = kk*32;
      int kg  = half*256 + kin;
      GLOAD_LDS16(sA + aoff0 + kin, aL0);
      GLOAD_LDS16(sA + aoff1 + kin, aL1);
      GLOAD_LDS16(wBase + boff0 + kg, bL0);
      GLOAD_LDS16(wBase + boff1 + kg, bL1);
      __syncthreads();
      s16x8 af[4], bf[4];
      #pragma unroll
      for (int mi=0;mi<4;mi++) af[mi] = *(const s16x8*)(aRead + mi*16*32);
      #pragma unroll
      for (int ni=0;ni<4;ni++) bf[ni] = *(const s16x8*)(bRead + ni*16*32);
      #pragma unroll
      for (int mi=0;mi<4;mi++)
        #pragma unroll
        for (int ni=0;ni<4;ni++)
          acc[mi][ni] = __builtin_amdgcn_mfma_f32_16x16x32_bf16(af[mi], bf[ni], acc[mi][ni], 0, 0, 0);
      __syncthreads();
    }
  }
  int fq = lane >> 4;
  #pragma unroll
  for (int ni=0;ni<4;ni++){
    int col = n0 + wc*64 + ni*16 + fr;
    float bv = be[col];
    #pragma unroll
    for (int mi=0;mi<4;mi++){
      int rowb = m0 + wr*64 + mi*16 + fq*4;
      f32x4 v = acc[mi][ni];
      #pragma unroll
      for (int j=0;j<4;j++){
        int row = rowb + j;
        if (row < cnt){
          float o = v[j] + bv;
          Oe[(size_t)row*DH + col] = f2bf(o);
        }
      }
    }
  }
}

// ---------------- combine (group-local sparse, write/accumulate) -----------
__global__ __launch_bounds__(256) void combine_spg_k(const u16* __restrict__ H3c,
    const int* __restrict__ ridx, const int* __restrict__ ppos,
    const float* __restrict__ rval, float* __restrict__ out,
    int N, int gBase, int ezCnt, int first){
  int n = blockIdx.x; if (n>=N) return;
  int f = threadIdx.x;
  size_t NS = (size_t)N*DH;
  size_t off = (size_t)n*DH + f;
  float acc = first ? 0.f : out[off];
  #pragma unroll
  for (int p=0;p<2;p++){
    int el = ridx[n*2+p] - gBase;
    if (el >= 0 && el < ezCnt)
      acc += rval[n*2+p] * bitsToF(((u32)H3c[(size_t)el*NS + (size_t)ppos[n*2+p]*DH + f])<<16);
  }
  out[off] = acc;
}

extern "C" void kernel_launch(void* const* d_in, const int* in_sizes, int n_in,
                              void* d_out, int out_size, void* d_ws, size_t ws_size,
                              hipStream_t stream)
{
  const float* x    = (const float*)d_in[0];
  const int*   ei   = (const int*)d_in[1];
  const int*   batch= (const int*)d_in[2];
  const float* encW = (const float*)d_in[3];
  const float* encb = (const float*)d_in[4];
  const float* rW1  = (const float*)d_in[5];
  const float* rb1  = (const float*)d_in[6];
  const float* rW2  = (const float*)d_in[7];
  const float* rb2  = (const float*)d_in[8];
  const float* Wrel = (const float*)d_in[9];
  const float* brel = (const float*)d_in[10];
  const float* Wroot= (const float*)d_in[11];
  int N = in_sizes[2];
  int E = in_sizes[1]/2;
  float* out = (float*)d_out;
  (void)n_in; (void)out_size;

  size_t NS = (size_t)N*DH;
  char* p = (char*)d_ws;
  auto carve = [&](size_t bytes)->char*{
    char* r = p; p += (bytes + 255) & ~(size_t)255; return r;
  };
  u16*  bh   = (u16*)carve(NS*2);
  u16*  WT   = (u16*)carve((size_t)3*NEXP*256*512*2);
  int*  deg  = (int*)carve((size_t)N*4 + 64*4);
  int*  ng   = deg + N;
  int*  eg   = ng + GNUM;
  int*  row_ptr = (int*)carve(((size_t)N+1)*4);
  int*  cursor  = (int*)carve((size_t)N*4);
  int*  csr     = (int*)carve((size_t)E*4);
  float* sizef  = (float*)carve(GNUM*2*4);
  int*  ridx    = (int*)carve((size_t)N*2*4);
  float* rvalv  = (float*)carve((size_t)N*2*4);
  int*  ecnt    = (int*)carve(NEXP*4);
  int*  plist   = (int*)carve((size_t)NEXP*N*4);
  int*  ppos    = (int*)carve((size_t)N*2*4);
  u16*  A0      = (u16*)carve(NS*2);
  size_t baseUsed = (size_t)(p - (char*)d_ws);

  int EZ = 0;
  for (int cand = NEXP; cand >= 1; cand >>= 1){
    if (baseUsed + (size_t)cand*3*NS*2 <= ws_size){ EZ = cand; break; }
  }
  if (EZ == 0){ mark_fail_k<<<1,1,0,stream>>>(out); return; }
  int ezShift = (EZ==8)?3 : (EZ==4)?2 : (EZ==2)?1 : 0;

  u16* Abuf = (u16*)carve((size_t)EZ*NS*2);   // dense A1 / compact A2
  u16* Hc   = (u16*)carve((size_t)EZ*NS*2);   // H1 / compact root
  u16* Hn   = (u16*)carve((size_t)EZ*NS*2);   // H2 / compact H3
  float* hf; float* rh;
  if (EZ >= 2){ hf = (float*)Abuf; rh = (float*)Hn; }
  else {
    hf = (float*)carve(NS*4);
    rh = (float*)carve(NS*4);
    if ((size_t)(p - (char*)d_ws) > ws_size){ mark_fail_k<<<1,1,0,stream>>>(out); return; }
  }

  hipMemsetAsync(deg, 0, (size_t)N*4 + (size_t)2*GNUM*4, stream);
  hipMemsetAsync(ecnt, 0, NEXP*4, stream);

  int eb = (E + 255)/256;
  count_edges_k<<<eb, 256, 0, stream>>>(ei, batch, deg, eg, E);
  count_nodes_k<<<(N+255)/256, 256, 0, stream>>>(batch, ng, N);
  scan_deg_k<<<1, SCAN_T, 0, stream>>>(deg, row_ptr, cursor, N);
  scatter_edges_k<<<eb, 256, 0, stream>>>(ei, cursor, csr, E);
  size_feats_k<<<1, 64, 0, stream>>>(ng, eg, sizef);
  encoder_k<<<N, 256, 0, stream>>>(x, encW, encb, hf, bh, N);
  convw_k<<<dim3(16,2,3*NEXP), dim3(64,4), 0, stream>>>(Wrel, Wroot, WT);
  router1_k<<<(N+R1N-1)/R1N, 256, 0, stream>>>(hf, sizef, batch, rW1, rb1, rh, N);
  router2_k<<<(N+3)/4, 256, 0, stream>>>(rh, rW2, rb2, ridx, rvalv, N);
  rsort_k<<<(N+255)/256, 256, 0, stream>>>(ridx, ecnt, plist, ppos, N);

  int aggx = (N+3)/4;
  int mt128 = (N+127)/128;
  const size_t WE = (size_t)256*512;

  agg0_k<<<aggx, 256, 0, stream>>>(bh, A0, row_ptr, csr, N);

  int gq = aggx*EZ;   // blocks per quarter dispatch (pinned 1D grid)

  for (int g = 0; g < NEXP; g += EZ){
    // layer 0 (dense BK64): shared A0/bh -> Hc (H1, relu)
    gemm0g_k<<<dim3(mt128,2,EZ), 256, 0, stream>>>(A0, bh,
        WT + ((size_t)0*NEXP + g)*WE, brel + (0*NEXP + g)*256, Hc, N);
    // layer 1: column-quartered, XCD-pinned gather Hc -> Abuf
    for (int q = 0; q < 4; ++q)
      agg1q_k<<<gq, 256, 0, stream>>>(Hc, Abuf, row_ptr, csr, N, q*64, EZ-1, ezShift);
    // layer-1 GEMM (dense BK64) -> Hn (H2, relu)
    gemm1g_k<<<dim3(mt128,2,EZ), 256, 0, stream>>>(Abuf, Hc,
        WT + ((size_t)1*NEXP + g)*WE, brel + (1*NEXP + g)*256, Hn, N);
    // layer 2 (routing-sparse): quartered compact gather Hn -> Abuf, root -> Hc
    for (int q = 0; q < 4; ++q)
      agg2q_k<<<gq, 256, 0, stream>>>(Hn, Abuf, Hc, row_ptr, csr,
          plist, ecnt, N, g, q*64, EZ-1, ezShift);
    gemm2sg_k<<<dim3(mt128,2,EZ), 256, 0, stream>>>(Abuf, Hc,
        WT + ((size_t)2*NEXP + g)*WE, brel + (2*NEXP + g)*256, Hn, ecnt, N, g);
    // routed combine (write on first group, accumulate after)
    combine_spg_k<<<N, 256, 0, stream>>>(Hn, ridx, ppos, rvalv, out, N, g, EZ, g==0);
  }
}

// Round 17
// 1813.579 us; speedup vs baseline: 1.2047x; 1.2047x over previous
//
#include <hip/hip_runtime.h>
#include <hip/hip_bf16.h>
#include <math.h>

#define NEXP 8
#define GNUM 16
#define DH 256

typedef __attribute__((ext_vector_type(8))) short s16x8;
typedef __attribute__((ext_vector_type(4))) float f32x4;
typedef unsigned short u16;
typedef unsigned int u32;

__device__ __forceinline__ float bitsToF(u32 b){ union{u32 u; float f;} c; c.u=b; return c.f; }
__device__ __forceinline__ u16 f2bf(float f){
  union{float f; u32 u;} c; c.f=f;
  u32 r = c.u + 0x7fffu + ((c.u>>16)&1u);
  return (u16)(r>>16);
}

#define GLOAD_LDS16(gp, lp) __builtin_amdgcn_global_load_lds( \
    (const __attribute__((address_space(1))) unsigned int*)(gp), \
    (__attribute__((address_space(3))) unsigned int*)(lp), 16, 0, 0)

// ---------------- CSR build ----------------
__global__ void count_edges_k(const int* __restrict__ ei, const int* __restrict__ batch,
                              int* __restrict__ deg, int* __restrict__ eg, int E){
  __shared__ int leg[GNUM];
  int t = threadIdx.x;
  if (t < GNUM) leg[t] = 0;
  __syncthreads();
  int i = blockIdx.x*blockDim.x + t;
  if (i < E){
    int s = ei[i];
    int d = ei[E + i];
    atomicAdd(&deg[d], 1);
    atomicAdd(&leg[batch[s]], 1);
  }
  __syncthreads();
  if (t < GNUM){ int v = leg[t]; if (v) atomicAdd(&eg[t], v); }
}

__global__ void count_nodes_k(const int* __restrict__ batch, int* __restrict__ ng, int N){
  __shared__ int lng[GNUM];
  int t = threadIdx.x;
  if (t < GNUM) lng[t] = 0;
  __syncthreads();
  int i = blockIdx.x*blockDim.x + t;
  if (i < N) atomicAdd(&lng[batch[i]], 1);
  __syncthreads();
  if (t < GNUM){ int v = lng[t]; if (v) atomicAdd(&ng[t], v); }
}

#define SCAN_T 1024
#define SCAN_CH 32
__global__ __launch_bounds__(1024) void scan_deg_k(const int* __restrict__ deg,
    int* __restrict__ row_ptr, int* __restrict__ cursor, int N){
  __shared__ int part[SCAN_T];
  int t = threadIdx.x;
  int base = t*SCAN_CH;
  int loc[SCAN_CH];
  int s = 0;
  #pragma unroll
  for (int j=0;j<SCAN_CH;j++){
    int i = base+j;
    int v = (i<N)? deg[i] : 0;
    loc[j] = s; s += v;
  }
  part[t] = s;
  __syncthreads();
  for (int off=1; off<SCAN_T; off<<=1){
    int add = (t>=off)? part[t-off] : 0;
    __syncthreads();
    part[t] += add;
    __syncthreads();
  }
  int ex = (t==0)? 0 : part[t-1];
  #pragma unroll
  for (int j=0;j<SCAN_CH;j++){
    int i = base+j;
    if (i<N){ int v = ex + loc[j]; row_ptr[i]=v; cursor[i]=v; }
  }
  if (t == SCAN_T-1) row_ptr[N] = part[SCAN_T-1];
}

__global__ void scatter_edges_k(const int* __restrict__ ei, int* __restrict__ cursor,
                                int* __restrict__ csr_src, int E){
  int i = blockIdx.x*blockDim.x + threadIdx.x;
  if (i>=E) return;
  int s = ei[i];
  int d = ei[E + i];
  int pos = atomicAdd(&cursor[d], 1);
  csr_src[pos] = s;
}

__global__ void size_feats_k(const int* __restrict__ ng, const int* __restrict__ eg,
                             float* __restrict__ sizef){
  int g = threadIdx.x;
  if (g < GNUM){
    sizef[g*2]   = logf(fmaxf((float)ng[g], 1.f));
    sizef[g*2+1] = logf(fmaxf((float)eg[g], 1.f));
  }
}

__global__ void mark_fail_k(float* out){ out[0] = __builtin_nanf(""); }

// ---------------- encoder ----------------
__global__ __launch_bounds__(256) void encoder_k(const float* __restrict__ x,
    const float* __restrict__ W, const float* __restrict__ b,
    float* __restrict__ hf, u16* __restrict__ bh, int N){
  int n = blockIdx.x; if (n>=N) return;
  int f = threadIdx.x;
  float acc = b[f];
  #pragma unroll
  for (int k=0;k<6;k++) acc += x[n*6+k]*W[k*DH+f];
  acc = fmaxf(acc, 0.f);
  hf[(size_t)n*DH+f] = acc;
  bh[(size_t)n*DH+f] = f2bf(acc);
}

// ---------------- weight convert ----------------
__global__ __launch_bounds__(256) void convw_k(const float* __restrict__ Wrel,
    const float* __restrict__ Wroot, u16* __restrict__ WT){
  __shared__ float tile[64][65];
  int tx = threadIdx.x;
  int ty = threadIdx.y;
  int kt = blockIdx.x & 3, ct = blockIdx.x >> 2;
  int srcRoot = blockIdx.y;
  int le = blockIdx.z;
  const float* src = (srcRoot ? Wroot : Wrel) + (size_t)le*65536;
  #pragma unroll
  for (int i=0;i<16;i++){
    int kl = ty + i*4;
    tile[kl][tx] = src[(size_t)(kt*64 + kl)*256 + ct*64 + tx];
  }
  __syncthreads();
  u16* dst = WT + (size_t)le*131072 + (srcRoot ? 256 : 0) + kt*64;
  #pragma unroll
  for (int i=0;i<16;i++){
    int cl = ty + i*4;
    dst[(size_t)(ct*64 + cl)*512 + tx] = f2bf(tile[tx][cl]);
  }
}

// ---------------- router layer 1 ----------------
#define R1N 32
__global__ __launch_bounds__(256) void router1_k(
    const float* __restrict__ hf, const float* __restrict__ sizef,
    const int* __restrict__ batch,
    const float* __restrict__ W1, const float* __restrict__ b1,
    float* __restrict__ rh, int N)
{
  __shared__ float xin[R1N][264];
  int t = threadIdx.x;
  int lane = t & 63, w = t >> 6;
  int n0 = blockIdx.x * R1N;
  #pragma unroll
  for (int i=0;i<R1N;i++){
    int n = n0 + i;
    xin[i][t] = (n<N) ? hf[(size_t)n*DH + t] : 0.f;
  }
  if (t < R1N){
    int n = n0 + t;
    int g = (n<N) ? (int)batch[n] : 0;
    xin[t][256] = sizef[g*2];
    xin[t][257] = sizef[g*2+1];
    xin[t][258] = 0.f; xin[t][259] = 0.f;
    xin[t][260] = 0.f; xin[t][261] = 0.f; xin[t][262] = 0.f; xin[t][263] = 0.f;
  }
  __syncthreads();

  int wn = w*8;
  float bb[4];
  #pragma unroll
  for (int c=0;c<4;c++) bb[c] = b1[lane + c*64];
  float acc[8][4];
  #pragma unroll
  for (int i=0;i<8;i++)
    #pragma unroll
    for (int c=0;c<4;c++) acc[i][c] = bb[c];

  #pragma unroll 2
  for (int k4=0; k4<256; k4+=4){
    float w4[4][4];
    #pragma unroll
    for (int j=0;j<4;j++)
      #pragma unroll
      for (int c=0;c<4;c++)
        w4[j][c] = W1[(size_t)(k4+j)*DH + lane + c*64];
    #pragma unroll
    for (int i=0;i<8;i++){
      f32x4 xv = *(const f32x4*)&xin[wn+i][k4];
      #pragma unroll
      for (int j=0;j<4;j++)
        #pragma unroll
        for (int c=0;c<4;c++)
          acc[i][c] += xv[j]*w4[j][c];
    }
  }
  float w256[4], w257[4];
  #pragma unroll
  for (int c=0;c<4;c++){
    w256[c] = W1[(size_t)256*DH + lane + c*64];
    w257[c] = W1[(size_t)257*DH + lane + c*64];
  }
  #pragma unroll
  for (int i=0;i<8;i++){
    float s0 = xin[wn+i][256], s1 = xin[wn+i][257];
    #pragma unroll
    for (int c=0;c<4;c++) acc[i][c] += s0*w256[c] + s1*w257[c];
  }
  #pragma unroll
  for (int i=0;i<8;i++){
    int n = n0 + wn + i;
    if (n < N){
      #pragma unroll
      for (int c=0;c<4;c++)
        rh[(size_t)n*DH + lane + c*64] = fmaxf(acc[i][c], 0.f);
    }
  }
}

// ---------------- router layer 2 + softmax + top2 ----------------
__global__ __launch_bounds__(256) void router2_k(
    const float* __restrict__ rh, const float* __restrict__ W2,
    const float* __restrict__ b2,
    int* __restrict__ ridx, float* __restrict__ rval, int N)
{
  __shared__ float w2s[NEXP][260];
  int t = threadIdx.x;
  for (int i=t; i<NEXP*DH; i+=256){
    int e = i >> 8, k = i & 255;
    w2s[e][k] = W2[(size_t)k*NEXP + e];
  }
  __syncthreads();
  int lane = t & 63, w = t >> 6;
  int n = blockIdx.x*4 + w;
  if (n >= N) return;
  const float* r = rh + (size_t)n*DH;
  float p[NEXP];
  #pragma unroll
  for (int e=0;e<NEXP;e++) p[e] = 0.f;
  #pragma unroll
  for (int c=0;c<4;c++){
    int k = lane + c*64;
    float rv = r[k];
    #pragma unroll
    for (int e=0;e<NEXP;e++) p[e] += rv * w2s[e][k];
  }
  #pragma unroll
  for (int off=1; off<64; off<<=1){
    #pragma unroll
    for (int e=0;e<NEXP;e++) p[e] += __shfl_xor(p[e], off, 64);
  }
  if (lane == 0){
    float l0[NEXP];
    #pragma unroll
    for (int e=0;e<NEXP;e++) l0[e] = p[e] + b2[e];
    float m = l0[0];
    #pragma unroll
    for (int e=1;e<NEXP;e++) m = fmaxf(m, l0[e]);
    float ex[NEXP];
    #pragma unroll
    for (int e=0;e<NEXP;e++) ex[e] = expf(l0[e]-m);
    int e0=0; float b0v=ex[0];
    #pragma unroll
    for (int e=1;e<NEXP;e++) if (ex[e]>b0v){b0v=ex[e]; e0=e;}
    int e1=(e0==0)?1:0; float b1v=ex[e1];
    #pragma unroll
    for (int e=0;e<NEXP;e++) if (e!=e0 && ex[e]>b1v){b1v=ex[e]; e1=e;}
    float sv = b0v + b1v;
    rval[n*2]   = b0v/sv;
    rval[n*2+1] = b1v/sv;
    ridx[n*2]   = e0;
    ridx[n*2+1] = e1;
  }
}

// ---------------- routing scatter (hierarchical) ----------------
__global__ __launch_bounds__(256) void rsort_k(const int* __restrict__ ridx,
    int* __restrict__ cnt, int* __restrict__ plist, int* __restrict__ ppos, int N){
  __shared__ int lcnt[NEXP];
  __shared__ int lbase[NEXP];
  int t = threadIdx.x;
  int n = blockIdx.x*256 + t;
  if (t < NEXP) lcnt[t] = 0;
  __syncthreads();
  int e0=0, e1=0, o0=0, o1=0;
  if (n < N){
    e0 = ridx[n*2];
    e1 = ridx[n*2+1];
    o0 = atomicAdd(&lcnt[e0], 1);
    o1 = atomicAdd(&lcnt[e1], 1);
  }
  __syncthreads();
  if (t < NEXP) lbase[t] = atomicAdd(&cnt[t], lcnt[t]);
  __syncthreads();
  if (n < N){
    int p0 = lbase[e0] + o0;
    int p1 = lbase[e1] + o1;
    plist[(size_t)e0*N + p0] = n;
    plist[(size_t)e1*N + p1] = n;
    ppos[n*2]   = p0;
    ppos[n*2+1] = p1;
  }
}

// ---------------- aggregation device body (full-row, for agg0) ------------
__device__ __forceinline__ void agg_row(const u16* __restrict__ H,
    u16* __restrict__ Arow, const int* __restrict__ row_ptr,
    const int* __restrict__ csr_src, int node, int lane){
  int beg = row_ptr[node], end = row_ptr[node+1];
  float a0=0.f,a1=0.f,a2=0.f,a3=0.f;
  const u16* Hl = H + (lane<<2);
  int i = beg;
  for (; i+8<=end; i+=8){
    int sarr[8];
    #pragma unroll
    for (int u=0;u<8;u++) sarr[u] = csr_src[i+u];
    #pragma unroll
    for (int u=0;u<8;u++){
      uint2 v = *(const uint2*)(Hl + ((size_t)sarr[u]<<8));
      a0 += bitsToF(v.x<<16);
      a1 += bitsToF(v.x & 0xffff0000u);
      a2 += bitsToF(v.y<<16);
      a3 += bitsToF(v.y & 0xffff0000u);
    }
  }
  for (; i<end; ++i){
    int s = csr_src[i];
    uint2 v = *(const uint2*)(Hl + ((size_t)s<<8));
    a0 += bitsToF(v.x<<16);
    a1 += bitsToF(v.x & 0xffff0000u);
    a2 += bitsToF(v.y<<16);
    a3 += bitsToF(v.y & 0xffff0000u);
  }
  uint2 o;
  o.x = ((u32)f2bf(a1)<<16) | f2bf(a0);
  o.y = ((u32)f2bf(a3)<<16) | f2bf(a2);
  *(uint2*)(Arow + (lane<<2)) = o;
}

// layer-0 shared aggregate (single L2-friendly table)
__global__ __launch_bounds__(256) void agg0_k(const u16* __restrict__ H,
    u16* __restrict__ A, const int* __restrict__ row_ptr,
    const int* __restrict__ csr_src, int N){
  int node = blockIdx.x*4 + (threadIdx.x>>6);
  if (node >= N) return;
  int lane = threadIdx.x & 63;
  agg_row(H, A + ((size_t)node<<8), row_ptr, csr_src, node, lane);
}

// ---------------- column-quartered gathers (unroll-8 ILP restored) ---------
// Per dispatch: cols [qoff, qoff+64) elems = 128B/row; per-expert working set
// N*128B = 3.84MB < 4MB XCD L2 (expert->XCD pinned -> L2-resident, verified
// by round-16 FETCH drop 365->18MB). Inner loop: 32 edges/iter, 8 unrolled
// independent loads per lane (e4 covers 4 edges; clamped-index batch loads).

__device__ __forceinline__ void aggq_core(const u16* __restrict__ Hq,
    const int* __restrict__ csr_src, int beg, int end, int e4,
    float& a0, float& a1, float& a2, float& a3){
  for (int i = beg; i < end; i += 32){
    int sarr[8];
    #pragma unroll
    for (int u=0;u<8;u++){
      int ii = i + e4 + 4*u;
      sarr[u] = csr_src[(ii < end) ? ii : (end-1)];
    }
    #pragma unroll
    for (int u=0;u<8;u++){
      uint2 v = *(const uint2*)(Hq + ((size_t)sarr[u]<<8));
      if (i + e4 + 4*u < end){
        a0 += bitsToF(v.x<<16);
        a1 += bitsToF(v.x & 0xffff0000u);
        a2 += bitsToF(v.y<<16);
        a3 += bitsToF(v.y & 0xffff0000u);
      }
    }
  }
}

// dense layer-1 quarter gather
__global__ __launch_bounds__(256) void agg1q_k(const u16* __restrict__ Hsrc,
    u16* __restrict__ Aout, const int* __restrict__ row_ptr,
    const int* __restrict__ csr_src, int N, int qoff, int ezMask, int ezShift){
  int bid = blockIdx.x;
  int el = bid & ezMask;
  int xb = bid >> ezShift;
  int node = xb*4 + (threadIdx.x>>6);
  if (node >= N) return;
  int lane = threadIdx.x & 63;
  int e4 = lane >> 4, c16 = lane & 15;
  size_t NS = (size_t)N*DH;
  const u16* Hq = Hsrc + (size_t)el*NS + qoff + (c16<<2);
  int beg = row_ptr[node], end = row_ptr[node+1];
  float a0=0.f,a1=0.f,a2=0.f,a3=0.f;
  aggq_core(Hq, csr_src, beg, end, e4, a0, a1, a2, a3);
  #pragma unroll
  for (int off=16; off<64; off<<=1){
    a0 += __shfl_xor(a0, off, 64);
    a1 += __shfl_xor(a1, off, 64);
    a2 += __shfl_xor(a2, off, 64);
    a3 += __shfl_xor(a3, off, 64);
  }
  if (e4 == 0){
    uint2 o;
    o.x = ((u32)f2bf(a1)<<16) | f2bf(a0);
    o.y = ((u32)f2bf(a3)<<16) | f2bf(a2);
    *(uint2*)(Aout + (size_t)el*NS + ((size_t)node<<8) + qoff + (c16<<2)) = o;
  }
}

// sparse layer-2 quarter gather + quartered root compaction
__global__ __launch_bounds__(256) void agg2q_k(const u16* __restrict__ Hsrc,
    u16* __restrict__ Aout, u16* __restrict__ Rout,
    const int* __restrict__ row_ptr, const int* __restrict__ csr_src,
    const int* __restrict__ plist, const int* __restrict__ cnt,
    int N, int gBase, int qoff, int ezMask, int ezShift){
  int bid = blockIdx.x;
  int el = bid & ezMask;
  int xb = bid >> ezShift;
  int idx = xb*4 + (threadIdx.x>>6);
  if (idx >= cnt[gBase + el]) return;
  int node = plist[(size_t)(gBase + el)*N + idx];
  int lane = threadIdx.x & 63;
  int e4 = lane >> 4, c16 = lane & 15;
  size_t NS = (size_t)N*DH;
  const u16* Hq = Hsrc + (size_t)el*NS + qoff + (c16<<2);
  int beg = row_ptr[node], end = row_ptr[node+1];
  float a0=0.f,a1=0.f,a2=0.f,a3=0.f;
  aggq_core(Hq, csr_src, beg, end, e4, a0, a1, a2, a3);
  #pragma unroll
  for (int off=16; off<64; off<<=1){
    a0 += __shfl_xor(a0, off, 64);
    a1 += __shfl_xor(a1, off, 64);
    a2 += __shfl_xor(a2, off, 64);
    a3 += __shfl_xor(a3, off, 64);
  }
  if (e4 == 0){
    uint2 rv = *(const uint2*)(Hq + ((size_t)node<<8));
    uint2 o;
    o.x = ((u32)f2bf(a1)<<16) | f2bf(a0);
    o.y = ((u32)f2bf(a3)<<16) | f2bf(a2);
    *(uint2*)(Aout + (size_t)el*NS + ((size_t)idx<<8) + qoff + (c16<<2)) = o;
    *(uint2*)(Rout + (size_t)el*NS + ((size_t)idx<<8) + qoff + (c16<<2)) = rv;
  }
}

// ---------------- dense GEMM, BK=64 (round-13 validated) ----------------
__device__ __forceinline__ void gemm_bk64_body(
    const u16* __restrict__ aBase, const u16* __restrict__ rBase,
    const u16* __restrict__ wBase, const float* __restrict__ be,
    u16* __restrict__ Oe, int N, int relu_flag, u16* As, u16* Bs)
{
  int tid = threadIdx.x;
  int lane = tid & 63, w = tid >> 6;
  int wr = w >> 1, wc = w & 1;
  int m0 = blockIdx.x * 128;
  int n0 = blockIdx.y * 128;

  int lr8 = lane >> 3;
  int p   = (lane & 7) ^ lr8;
  long long asrc[4]; u16* aL[4];
  long long bsrc[4]; u16* bL[4];
  #pragma unroll
  for (int j=0;j<4;j++){
    int c = w*4 + j;
    int arow = m0 + c*8 + lr8; if (arow >= N) arow = N-1;
    asrc[j] = (long long)arow*256 + p*8;
    aL[j] = As + (size_t)c*512;
    int bcol = n0 + c*8 + lr8;
    bsrc[j] = (long long)bcol*512 + p*8;
    bL[j] = Bs + (size_t)c*512;
  }

  f32x4 acc[4][4];
  #pragma unroll
  for (int a=0;a<4;a++)
    #pragma unroll
    for (int b=0;b<4;b++) acc[a][b] = (f32x4){0.f,0.f,0.f,0.f};

  int fr = lane & 15;
  int fkq = lane >> 4;

  #pragma unroll 1
  for (int kk=0; kk<8; ++kk){
    const u16* sA = (kk < 4) ? aBase : rBase;
    int koff = (kk & 3) * 64;
    #pragma unroll
    for (int j=0;j<4;j++){
      GLOAD_LDS16(sA + asrc[j] + koff, aL[j]);
      GLOAD_LDS16(wBase + bsrc[j] + kk*64, bL[j]);
    }
    __syncthreads();
    #pragma unroll
    for (int kin=0; kin<2; ++kin){
      unsigned fb = (unsigned)(fkq*16 + kin*64);
      s16x8 af[4], bf[4];
      #pragma unroll
      for (int mi=0;mi<4;mi++){
        int row = wr*64 + mi*16 + fr;
        unsigned byte = ((unsigned)row << 7) + (fb ^ (((unsigned)(row & 7)) << 4));
        af[mi] = *(const s16x8*)((const char*)As + byte);
      }
      #pragma unroll
      for (int ni=0;ni<4;ni++){
        int col = wc*64 + ni*16 + fr;
        unsigned byte = ((unsigned)col << 7) + (fb ^ (((unsigned)(col & 7)) << 4));
        bf[ni] = *(const s16x8*)((const char*)Bs + byte);
      }
      #pragma unroll
      for (int mi=0;mi<4;mi++)
        #pragma unroll
        for (int ni=0;ni<4;ni++)
          acc[mi][ni] = __builtin_amdgcn_mfma_f32_16x16x32_bf16(af[mi], bf[ni], acc[mi][ni], 0, 0, 0);
    }
    __syncthreads();
  }

  int fq = lane >> 4;
  #pragma unroll
  for (int ni=0;ni<4;ni++){
    int col = n0 + wc*64 + ni*16 + fr;
    float bv = be[col];
    #pragma unroll
    for (int mi=0;mi<4;mi++){
      int rowb = m0 + wr*64 + mi*16 + fq*4;
      f32x4 v = acc[mi][ni];
      #pragma unroll
      for (int j=0;j<4;j++){
        int row = rowb + j;
        if (row < N){
          float o = v[j] + bv;
          if (relu_flag) o = fmaxf(o, 0.f);
          Oe[(size_t)row*DH + col] = f2bf(o);
        }
      }
    }
  }
}

__global__ __launch_bounds__(256,2) void gemm0g_k(
    const u16* __restrict__ A0, const u16* __restrict__ bh,
    const u16* __restrict__ WT, const float* __restrict__ bias,
    u16* __restrict__ Hout, int N){
  __shared__ u16 As[128*64];
  __shared__ u16 Bs[128*64];
  int el = blockIdx.z;
  gemm_bk64_body(A0, bh, WT + (size_t)el*(256*512), bias + el*256,
                 Hout + (size_t)el*((size_t)N*DH), N, 1, As, Bs);
}
__global__ __launch_bounds__(256,2) void gemm1g_k(
    const u16* __restrict__ Aagg, const u16* __restrict__ Hroot,
    const u16* __restrict__ WT, const float* __restrict__ bias,
    u16* __restrict__ Hout, int N){
  __shared__ u16 As[128*64];
  __shared__ u16 Bs[128*64];
  int el = blockIdx.z;
  size_t NS = (size_t)N*DH;
  gemm_bk64_body(Aagg + (size_t)el*NS, Hroot + (size_t)el*NS,
                 WT + (size_t)el*(256*512), bias + el*256,
                 Hout + (size_t)el*NS, N, 1, As, Bs);
}

// sparse layer-2 GEMM (round-10/13 validated BK=32 body)
__global__ __launch_bounds__(256,2) void gemm2sg_k(
    const u16* __restrict__ Aagg, const u16* __restrict__ Rc,
    const u16* __restrict__ WT, const float* __restrict__ bias,
    u16* __restrict__ Hout, const int* __restrict__ cnte, int N, int gBase)
{
  __shared__ u16 As[128*32];
  __shared__ u16 Bs[128*32];
  int el = blockIdx.z;
  int cnt = cnte[gBase + el];
  int m0 = blockIdx.x * 128;
  if (m0 >= cnt) return;
  size_t NS = (size_t)N*DH;
  const u16* aBase = Aagg + (size_t)el*NS;
  const u16* rBase = Rc + (size_t)el*NS;
  const u16* wBase = WT + (size_t)el*(256*512);
  const float* be  = bias + el*256;
  u16* Oe = Hout + (size_t)el*NS;

  int tid = threadIdx.x;
  int lane = tid & 63, w = tid >> 6;
  int wr = w >> 1, wc = w & 1;
  int n0 = blockIdx.y * 128;

  int lrow = lane >> 2;
  int q8   = (((lane & 3) ^ ((lane >> 3) & 3))) * 8;
  int r0 = w*16 + lrow;
  int r1 = (w+4)*16 + lrow;
  int ai0 = m0 + r0; if (ai0 >= cnt) ai0 = cnt-1;
  int ai1 = m0 + r1; if (ai1 >= cnt) ai1 = cnt-1;
  long long aoff0 = (long long)ai0*256 + q8;
  long long aoff1 = (long long)ai1*256 + q8;
  long long boff0 = (long long)(n0 + r0)*512 + q8;
  long long boff1 = (long long)(n0 + r1)*512 + q8;
  u16* aL0 = As + (size_t)w*512;
  u16* aL1 = As + (size_t)(w+4)*512;
  u16* bL0 = Bs + (size_t)w*512;
  u16* bL1 = Bs + (size_t)(w+4)*512;

  f32x4 acc[4][4];
  #pragma unroll
  for (int a=0;a<4;a++)
    #pragma unroll
    for (int b=0;b<4;b++) acc[a][b] = (f32x4){0.f,0.f,0.f,0.f};

  int fr = lane & 15;
  int fk = (((lane >> 4) ^ ((fr >> 1) & 3))) * 8;
  const u16* aRead = As + (size_t)(wr*64 + fr)*32 + fk;
  const u16* bRead = Bs + (size_t)(wc*64 + fr)*32 + fk;

  #pragma unroll 1
  for (int half=0; half<2; ++half){
    const u16* sA = half ? rBase : aBase;
    #pragma unroll 1
    for (int kk=0; kk<8; ++kk){
      int kin = kk*32;
      int kg  = half*256 + kin;
      GLOAD_LDS16(sA + aoff0 + kin, aL0);
      GLOAD_LDS16(sA + aoff1 + kin, aL1);
      GLOAD_LDS16(wBase + boff0 + kg, bL0);
      GLOAD_LDS16(wBase + boff1 + kg, bL1);
      __syncthreads();
      s16x8 af[4], bf[4];
      #pragma unroll
      for (int mi=0;mi<4;mi++) af[mi] = *(const s16x8*)(aRead + mi*16*32);
      #pragma unroll
      for (int ni=0;ni<4;ni++) bf[ni] = *(const s16x8*)(bRead + ni*16*32);
      #pragma unroll
      for (int mi=0;mi<4;mi++)
        #pragma unroll
        for (int ni=0;ni<4;ni++)
          acc[mi][ni] = __builtin_amdgcn_mfma_f32_16x16x32_bf16(af[mi], bf[ni], acc[mi][ni], 0, 0, 0);
      __syncthreads();
    }
  }
  int fq = lane >> 4;
  #pragma unroll
  for (int ni=0;ni<4;ni++){
    int col = n0 + wc*64 + ni*16 + fr;
    float bv = be[col];
    #pragma unroll
    for (int mi=0;mi<4;mi++){
      int rowb = m0 + wr*64 + mi*16 + fq*4;
      f32x4 v = acc[mi][ni];
      #pragma unroll
      for (int j=0;j<4;j++){
        int row = rowb + j;
        if (row < cnt){
          float o = v[j] + bv;
          Oe[(size_t)row*DH + col] = f2bf(o);
        }
      }
    }
  }
}

// ---------------- combine (group-local sparse, write/accumulate) -----------
__global__ __launch_bounds__(256) void combine_spg_k(const u16* __restrict__ H3c,
    const int* __restrict__ ridx, const int* __restrict__ ppos,
    const float* __restrict__ rval, float* __restrict__ out,
    int N, int gBase, int ezCnt, int first){
  int n = blockIdx.x; if (n>=N) return;
  int f = threadIdx.x;
  size_t NS = (size_t)N*DH;
  size_t off = (size_t)n*DH + f;
  float acc = first ? 0.f : out[off];
  #pragma unroll
  for (int p=0;p<2;p++){
    int el = ridx[n*2+p] - gBase;
    if (el >= 0 && el < ezCnt)
      acc += rval[n*2+p] * bitsToF(((u32)H3c[(size_t)el*NS + (size_t)ppos[n*2+p]*DH + f])<<16);
  }
  out[off] = acc;
}

extern "C" void kernel_launch(void* const* d_in, const int* in_sizes, int n_in,
                              void* d_out, int out_size, void* d_ws, size_t ws_size,
                              hipStream_t stream)
{
  const float* x    = (const float*)d_in[0];
  const int*   ei   = (const int*)d_in[1];
  const int*   batch= (const int*)d_in[2];
  const float* encW = (const float*)d_in[3];
  const float* encb = (const float*)d_in[4];
  const float* rW1  = (const float*)d_in[5];
  const float* rb1  = (const float*)d_in[6];
  const float* rW2  = (const float*)d_in[7];
  const float* rb2  = (const float*)d_in[8];
  const float* Wrel = (const float*)d_in[9];
  const float* brel = (const float*)d_in[10];
  const float* Wroot= (const float*)d_in[11];
  int N = in_sizes[2];
  int E = in_sizes[1]/2;
  float* out = (float*)d_out;
  (void)n_in; (void)out_size;

  size_t NS = (size_t)N*DH;
  char* p = (char*)d_ws;
  auto carve = [&](size_t bytes)->char*{
    char* r = p; p += (bytes + 255) & ~(size_t)255; return r;
  };
  u16*  bh   = (u16*)carve(NS*2);
  u16*  WT   = (u16*)carve((size_t)3*NEXP*256*512*2);
  int*  deg  = (int*)carve((size_t)N*4 + 64*4);
  int*  ng   = deg + N;
  int*  eg   = ng + GNUM;
  int*  row_ptr = (int*)carve(((size_t)N+1)*4);
  int*  cursor  = (int*)carve((size_t)N*4);
  int*  csr     = (int*)carve((size_t)E*4);
  float* sizef  = (float*)carve(GNUM*2*4);
  int*  ridx    = (int*)carve((size_t)N*2*4);
  float* rvalv  = (float*)carve((size_t)N*2*4);
  int*  ecnt    = (int*)carve(NEXP*4);
  int*  plist   = (int*)carve((size_t)NEXP*N*4);
  int*  ppos    = (int*)carve((size_t)N*2*4);
  u16*  A0      = (u16*)carve(NS*2);
  size_t baseUsed = (size_t)(p - (char*)d_ws);

  int EZ = 0;
  for (int cand = NEXP; cand >= 1; cand >>= 1){
    if (baseUsed + (size_t)cand*3*NS*2 <= ws_size){ EZ = cand; break; }
  }
  if (EZ == 0){ mark_fail_k<<<1,1,0,stream>>>(out); return; }
  int ezShift = (EZ==8)?3 : (EZ==4)?2 : (EZ==2)?1 : 0;

  u16* Abuf = (u16*)carve((size_t)EZ*NS*2);   // dense A1 / compact A2
  u16* Hc   = (u16*)carve((size_t)EZ*NS*2);   // H1 / compact root
  u16* Hn   = (u16*)carve((size_t)EZ*NS*2);   // H2 / compact H3
  float* hf; float* rh;
  if (EZ >= 2){ hf = (float*)Abuf; rh = (float*)Hn; }
  else {
    hf = (float*)carve(NS*4);
    rh = (float*)carve(NS*4);
    if ((size_t)(p - (char*)d_ws) > ws_size){ mark_fail_k<<<1,1,0,stream>>>(out); return; }
  }

  hipMemsetAsync(deg, 0, (size_t)N*4 + (size_t)2*GNUM*4, stream);
  hipMemsetAsync(ecnt, 0, NEXP*4, stream);

  int eb = (E + 255)/256;
  count_edges_k<<<eb, 256, 0, stream>>>(ei, batch, deg, eg, E);
  count_nodes_k<<<(N+255)/256, 256, 0, stream>>>(batch, ng, N);
  scan_deg_k<<<1, SCAN_T, 0, stream>>>(deg, row_ptr, cursor, N);
  scatter_edges_k<<<eb, 256, 0, stream>>>(ei, cursor, csr, E);
  size_feats_k<<<1, 64, 0, stream>>>(ng, eg, sizef);
  encoder_k<<<N, 256, 0, stream>>>(x, encW, encb, hf, bh, N);
  convw_k<<<dim3(16,2,3*NEXP), dim3(64,4), 0, stream>>>(Wrel, Wroot, WT);
  router1_k<<<(N+R1N-1)/R1N, 256, 0, stream>>>(hf, sizef, batch, rW1, rb1, rh, N);
  router2_k<<<(N+3)/4, 256, 0, stream>>>(rh, rW2, rb2, ridx, rvalv, N);
  rsort_k<<<(N+255)/256, 256, 0, stream>>>(ridx, ecnt, plist, ppos, N);

  int aggx = (N+3)/4;
  int mt128 = (N+127)/128;
  const size_t WE = (size_t)256*512;

  agg0_k<<<aggx, 256, 0, stream>>>(bh, A0, row_ptr, csr, N);

  int gq = aggx*EZ;   // blocks per quarter dispatch (pinned 1D grid)

  for (int g = 0; g < NEXP; g += EZ){
    // layer 0 (dense BK64): shared A0/bh -> Hc (H1, relu)
    gemm0g_k<<<dim3(mt128,2,EZ), 256, 0, stream>>>(A0, bh,
        WT + ((size_t)0*NEXP + g)*WE, brel + (0*NEXP + g)*256, Hc, N);
    // layer 1: column-quartered, XCD-pinned gather Hc -> Abuf
    for (int q = 0; q < 4; ++q)
      agg1q_k<<<gq, 256, 0, stream>>>(Hc, Abuf, row_ptr, csr, N, q*64, EZ-1, ezShift);
    // layer-1 GEMM (dense BK64) -> Hn (H2, relu)
    gemm1g_k<<<dim3(mt128,2,EZ), 256, 0, stream>>>(Abuf, Hc,
        WT + ((size_t)1*NEXP + g)*WE, brel + (1*NEXP + g)*256, Hn, N);
    // layer 2 (routing-sparse): quartered compact gather Hn -> Abuf, root -> Hc
    for (int q = 0; q < 4; ++q)
      agg2q_k<<<gq, 256, 0, stream>>>(Hn, Abuf, Hc, row_ptr, csr,
          plist, ecnt, N, g, q*64, EZ-1, ezShift);
    gemm2sg_k<<<dim3(mt128,2,EZ), 256, 0, stream>>>(Abuf, Hc,
        WT + ((size_t)2*NEXP + g)*WE, brel + (2*NEXP + g)*256, Hn, ecnt, N, g);
    // routed combine (write on first group, accumulate after)
    combine_spg_k<<<N, 256, 0, stream>>>(Hn, ridx, ppos, rvalv, out, N, g, EZ, g==0);
  }
}

// Round 18
// 1293.761 us; speedup vs baseline: 1.6887x; 1.4018x over previous
//
#include <hip/hip_runtime.h>
#include <hip/hip_bf16.h>
#include <math.h>

#define NEXP 8
#define GNUM 16
#define DH 256

typedef __attribute__((ext_vector_type(8))) short s16x8;
typedef __attribute__((ext_vector_type(4))) float f32x4;
typedef unsigned short u16;
typedef unsigned int u32;

__device__ __forceinline__ float bitsToF(u32 b){ union{u32 u; float f;} c; c.u=b; return c.f; }
__device__ __forceinline__ u16 f2bf(float f){
  union{float f; u32 u;} c; c.f=f;
  u32 r = c.u + 0x7fffu + ((c.u>>16)&1u);
  return (u16)(r>>16);
}

#define GLOAD_LDS16(gp, lp) __builtin_amdgcn_global_load_lds( \
    (const __attribute__((address_space(1))) unsigned int*)(gp), \
    (__attribute__((address_space(3))) unsigned int*)(lp), 16, 0, 0)

// ---------------- CSR build ----------------
__global__ void count_edges_k(const int* __restrict__ ei, const int* __restrict__ batch,
                              int* __restrict__ deg, int* __restrict__ eg, int E){
  __shared__ int leg[GNUM];
  int t = threadIdx.x;
  if (t < GNUM) leg[t] = 0;
  __syncthreads();
  int i = blockIdx.x*blockDim.x + t;
  if (i < E){
    int s = ei[i];
    int d = ei[E + i];
    atomicAdd(&deg[d], 1);
    atomicAdd(&leg[batch[s]], 1);
  }
  __syncthreads();
  if (t < GNUM){ int v = leg[t]; if (v) atomicAdd(&eg[t], v); }
}

__global__ void count_nodes_k(const int* __restrict__ batch, int* __restrict__ ng, int N){
  __shared__ int lng[GNUM];
  int t = threadIdx.x;
  if (t < GNUM) lng[t] = 0;
  __syncthreads();
  int i = blockIdx.x*blockDim.x + t;
  if (i < N) atomicAdd(&lng[batch[i]], 1);
  __syncthreads();
  if (t < GNUM){ int v = lng[t]; if (v) atomicAdd(&ng[t], v); }
}

#define SCAN_T 1024
#define SCAN_CH 32
__global__ __launch_bounds__(1024) void scan_deg_k(const int* __restrict__ deg,
    int* __restrict__ row_ptr, int* __restrict__ cursor, int N){
  __shared__ int part[SCAN_T];
  int t = threadIdx.x;
  int base = t*SCAN_CH;
  int loc[SCAN_CH];
  int s = 0;
  #pragma unroll
  for (int j=0;j<SCAN_CH;j++){
    int i = base+j;
    int v = (i<N)? deg[i] : 0;
    loc[j] = s; s += v;
  }
  part[t] = s;
  __syncthreads();
  for (int off=1; off<SCAN_T; off<<=1){
    int add = (t>=off)? part[t-off] : 0;
    __syncthreads();
    part[t] += add;
    __syncthreads();
  }
  int ex = (t==0)? 0 : part[t-1];
  #pragma unroll
  for (int j=0;j<SCAN_CH;j++){
    int i = base+j;
    if (i<N){ int v = ex + loc[j]; row_ptr[i]=v; cursor[i]=v; }
  }
  if (t == SCAN_T-1) row_ptr[N] = part[SCAN_T-1];
}

__global__ void scatter_edges_k(const int* __restrict__ ei, int* __restrict__ cursor,
                                int* __restrict__ csr_src, int E){
  int i = blockIdx.x*blockDim.x + threadIdx.x;
  if (i>=E) return;
  int s = ei[i];
  int d = ei[E + i];
  int pos = atomicAdd(&cursor[d], 1);
  csr_src[pos] = s;
}

__global__ void size_feats_k(const int* __restrict__ ng, const int* __restrict__ eg,
                             float* __restrict__ sizef){
  int g = threadIdx.x;
  if (g < GNUM){
    sizef[g*2]   = logf(fmaxf((float)ng[g], 1.f));
    sizef[g*2+1] = logf(fmaxf((float)eg[g], 1.f));
  }
}

__global__ void mark_fail_k(float* out){ out[0] = __builtin_nanf(""); }

// ---------------- encoder ----------------
__global__ __launch_bounds__(256) void encoder_k(const float* __restrict__ x,
    const float* __restrict__ W, const float* __restrict__ b,
    float* __restrict__ hf, u16* __restrict__ bh, int N){
  int n = blockIdx.x; if (n>=N) return;
  int f = threadIdx.x;
  float acc = b[f];
  #pragma unroll
  for (int k=0;k<6;k++) acc += x[n*6+k]*W[k*DH+f];
  acc = fmaxf(acc, 0.f);
  hf[(size_t)n*DH+f] = acc;
  bh[(size_t)n*DH+f] = f2bf(acc);
}

// ---------------- weight convert ----------------
__global__ __launch_bounds__(256) void convw_k(const float* __restrict__ Wrel,
    const float* __restrict__ Wroot, u16* __restrict__ WT){
  __shared__ float tile[64][65];
  int tx = threadIdx.x;
  int ty = threadIdx.y;
  int kt = blockIdx.x & 3, ct = blockIdx.x >> 2;
  int srcRoot = blockIdx.y;
  int le = blockIdx.z;
  const float* src = (srcRoot ? Wroot : Wrel) + (size_t)le*65536;
  #pragma unroll
  for (int i=0;i<16;i++){
    int kl = ty + i*4;
    tile[kl][tx] = src[(size_t)(kt*64 + kl)*256 + ct*64 + tx];
  }
  __syncthreads();
  u16* dst = WT + (size_t)le*131072 + (srcRoot ? 256 : 0) + kt*64;
  #pragma unroll
  for (int i=0;i<16;i++){
    int cl = ty + i*4;
    dst[(size_t)(ct*64 + cl)*512 + tx] = f2bf(tile[tx][cl]);
  }
}

// ---------------- router layer 1 ----------------
#define R1N 32
__global__ __launch_bounds__(256) void router1_k(
    const float* __restrict__ hf, const float* __restrict__ sizef,
    const int* __restrict__ batch,
    const float* __restrict__ W1, const float* __restrict__ b1,
    float* __restrict__ rh, int N)
{
  __shared__ float xin[R1N][264];
  int t = threadIdx.x;
  int lane = t & 63, w = t >> 6;
  int n0 = blockIdx.x * R1N;
  #pragma unroll
  for (int i=0;i<R1N;i++){
    int n = n0 + i;
    xin[i][t] = (n<N) ? hf[(size_t)n*DH + t] : 0.f;
  }
  if (t < R1N){
    int n = n0 + t;
    int g = (n<N) ? (int)batch[n] : 0;
    xin[t][256] = sizef[g*2];
    xin[t][257] = sizef[g*2+1];
    xin[t][258] = 0.f; xin[t][259] = 0.f;
    xin[t][260] = 0.f; xin[t][261] = 0.f; xin[t][262] = 0.f; xin[t][263] = 0.f;
  }
  __syncthreads();

  int wn = w*8;
  float bb[4];
  #pragma unroll
  for (int c=0;c<4;c++) bb[c] = b1[lane + c*64];
  float acc[8][4];
  #pragma unroll
  for (int i=0;i<8;i++)
    #pragma unroll
    for (int c=0;c<4;c++) acc[i][c] = bb[c];

  #pragma unroll 2
  for (int k4=0; k4<256; k4+=4){
    float w4[4][4];
    #pragma unroll
    for (int j=0;j<4;j++)
      #pragma unroll
      for (int c=0;c<4;c++)
        w4[j][c] = W1[(size_t)(k4+j)*DH + lane + c*64];
    #pragma unroll
    for (int i=0;i<8;i++){
      f32x4 xv = *(const f32x4*)&xin[wn+i][k4];
      #pragma unroll
      for (int j=0;j<4;j++)
        #pragma unroll
        for (int c=0;c<4;c++)
          acc[i][c] += xv[j]*w4[j][c];
    }
  }
  float w256[4], w257[4];
  #pragma unroll
  for (int c=0;c<4;c++){
    w256[c] = W1[(size_t)256*DH + lane + c*64];
    w257[c] = W1[(size_t)257*DH + lane + c*64];
  }
  #pragma unroll
  for (int i=0;i<8;i++){
    float s0 = xin[wn+i][256], s1 = xin[wn+i][257];
    #pragma unroll
    for (int c=0;c<4;c++) acc[i][c] += s0*w256[c] + s1*w257[c];
  }
  #pragma unroll
  for (int i=0;i<8;i++){
    int n = n0 + wn + i;
    if (n < N){
      #pragma unroll
      for (int c=0;c<4;c++)
        rh[(size_t)n*DH + lane + c*64] = fmaxf(acc[i][c], 0.f);
    }
  }
}

// ---------------- router layer 2 + softmax + top2 ----------------
__global__ __launch_bounds__(256) void router2_k(
    const float* __restrict__ rh, const float* __restrict__ W2,
    const float* __restrict__ b2,
    int* __restrict__ ridx, float* __restrict__ rval, int N)
{
  __shared__ float w2s[NEXP][260];
  int t = threadIdx.x;
  for (int i=t; i<NEXP*DH; i+=256){
    int e = i >> 8, k = i & 255;
    w2s[e][k] = W2[(size_t)k*NEXP + e];
  }
  __syncthreads();
  int lane = t & 63, w = t >> 6;
  int n = blockIdx.x*4 + w;
  if (n >= N) return;
  const float* r = rh + (size_t)n*DH;
  float p[NEXP];
  #pragma unroll
  for (int e=0;e<NEXP;e++) p[e] = 0.f;
  #pragma unroll
  for (int c=0;c<4;c++){
    int k = lane + c*64;
    float rv = r[k];
    #pragma unroll
    for (int e=0;e<NEXP;e++) p[e] += rv * w2s[e][k];
  }
  #pragma unroll
  for (int off=1; off<64; off<<=1){
    #pragma unroll
    for (int e=0;e<NEXP;e++) p[e] += __shfl_xor(p[e], off, 64);
  }
  if (lane == 0){
    float l0[NEXP];
    #pragma unroll
    for (int e=0;e<NEXP;e++) l0[e] = p[e] + b2[e];
    float m = l0[0];
    #pragma unroll
    for (int e=1;e<NEXP;e++) m = fmaxf(m, l0[e]);
    float ex[NEXP];
    #pragma unroll
    for (int e=0;e<NEXP;e++) ex[e] = expf(l0[e]-m);
    int e0=0; float b0v=ex[0];
    #pragma unroll
    for (int e=1;e<NEXP;e++) if (ex[e]>b0v){b0v=ex[e]; e0=e;}
    int e1=(e0==0)?1:0; float b1v=ex[e1];
    #pragma unroll
    for (int e=0;e<NEXP;e++) if (e!=e0 && ex[e]>b1v){b1v=ex[e]; e1=e;}
    float sv = b0v + b1v;
    rval[n*2]   = b0v/sv;
    rval[n*2+1] = b1v/sv;
    ridx[n*2]   = e0;
    ridx[n*2+1] = e1;
  }
}

// ---------------- routing scatter (hierarchical) ----------------
__global__ __launch_bounds__(256) void rsort_k(const int* __restrict__ ridx,
    int* __restrict__ cnt, int* __restrict__ plist, int* __restrict__ ppos, int N){
  __shared__ int lcnt[NEXP];
  __shared__ int lbase[NEXP];
  int t = threadIdx.x;
  int n = blockIdx.x*256 + t;
  if (t < NEXP) lcnt[t] = 0;
  __syncthreads();
  int e0=0, e1=0, o0=0, o1=0;
  if (n < N){
    e0 = ridx[n*2];
    e1 = ridx[n*2+1];
    o0 = atomicAdd(&lcnt[e0], 1);
    o1 = atomicAdd(&lcnt[e1], 1);
  }
  __syncthreads();
  if (t < NEXP) lbase[t] = atomicAdd(&cnt[t], lcnt[t]);
  __syncthreads();
  if (n < N){
    int p0 = lbase[e0] + o0;
    int p1 = lbase[e1] + o1;
    plist[(size_t)e0*N + p0] = n;
    plist[(size_t)e1*N + p1] = n;
    ppos[n*2]   = p0;
    ppos[n*2+1] = p1;
  }
}

// ---------------- aggregation device body ----------------
__device__ __forceinline__ void agg_row(const u16* __restrict__ H,
    u16* __restrict__ Arow, const int* __restrict__ row_ptr,
    const int* __restrict__ csr_src, int node, int lane){
  int beg = row_ptr[node], end = row_ptr[node+1];
  float a0=0.f,a1=0.f,a2=0.f,a3=0.f;
  const u16* Hl = H + (lane<<2);
  int i = beg;
  for (; i+8<=end; i+=8){
    int sarr[8];
    #pragma unroll
    for (int u=0;u<8;u++) sarr[u] = csr_src[i+u];
    #pragma unroll
    for (int u=0;u<8;u++){
      uint2 v = *(const uint2*)(Hl + ((size_t)sarr[u]<<8));
      a0 += bitsToF(v.x<<16);
      a1 += bitsToF(v.x & 0xffff0000u);
      a2 += bitsToF(v.y<<16);
      a3 += bitsToF(v.y & 0xffff0000u);
    }
  }
  for (; i<end; ++i){
    int s = csr_src[i];
    uint2 v = *(const uint2*)(Hl + ((size_t)s<<8));
    a0 += bitsToF(v.x<<16);
    a1 += bitsToF(v.x & 0xffff0000u);
    a2 += bitsToF(v.y<<16);
    a3 += bitsToF(v.y & 0xffff0000u);
  }
  uint2 o;
  o.x = ((u32)f2bf(a1)<<16) | f2bf(a0);
  o.y = ((u32)f2bf(a3)<<16) | f2bf(a2);
  *(uint2*)(Arow + (lane<<2)) = o;
}

// layer-0 shared aggregate
__global__ __launch_bounds__(256) void agg0_k(const u16* __restrict__ H,
    u16* __restrict__ A, const int* __restrict__ row_ptr,
    const int* __restrict__ csr_src, int N){
  int node = blockIdx.x*4 + (threadIdx.x>>6);
  if (node >= N) return;
  int lane = threadIdx.x & 63;
  agg_row(H, A + ((size_t)node<<8), row_ptr, csr_src, node, lane);
}

// layer-1 dense aggregate, expert->XCD pinned, node range [base, base+cnt)
__device__ __forceinline__ void agg1_body(const u16* __restrict__ Hsrc,
    u16* __restrict__ Aout, const int* __restrict__ row_ptr,
    const int* __restrict__ csr_src, int N, int base, int cntN,
    int ezMask, int ezShift){
  int bid = blockIdx.x;
  int el = bid & ezMask;
  int xb = bid >> ezShift;
  int node = base + xb*4 + (threadIdx.x>>6);
  if (node >= base + cntN) return;
  int lane = threadIdx.x & 63;
  size_t NS = (size_t)N*DH;
  agg_row(Hsrc + (size_t)el*NS, Aout + (size_t)el*NS + ((size_t)node<<8),
          row_ptr, csr_src, node, lane);
}
__global__ __launch_bounds__(256) void agg1a_k(const u16* __restrict__ Hsrc,
    u16* __restrict__ Aout, const int* __restrict__ row_ptr,
    const int* __restrict__ csr_src, int N, int base, int cntN,
    int ezMask, int ezShift){
  agg1_body(Hsrc, Aout, row_ptr, csr_src, N, base, cntN, ezMask, ezShift);
}
__global__ __launch_bounds__(256) void agg1b_k(const u16* __restrict__ Hsrc,
    u16* __restrict__ Aout, const int* __restrict__ row_ptr,
    const int* __restrict__ csr_src, int N, int base, int cntN,
    int ezMask, int ezShift){
  agg1_body(Hsrc, Aout, row_ptr, csr_src, N, base, cntN, ezMask, ezShift);
}

// sparse (routed-rows) aggregate + root compaction, group-local
__global__ __launch_bounds__(256) void agg2sg_k(const u16* __restrict__ Hsrc,
    u16* __restrict__ Aout, u16* __restrict__ Rout,
    const int* __restrict__ row_ptr, const int* __restrict__ csr_src,
    const int* __restrict__ plist, const int* __restrict__ cnt,
    int N, int gBase){
  int el = blockIdx.y;
  int idx = blockIdx.x*4 + (threadIdx.x>>6);
  if (idx >= cnt[gBase + el]) return;
  int node = plist[(size_t)(gBase + el)*N + idx];
  size_t NS = (size_t)N*DH;
  const u16* H = Hsrc + (size_t)el*NS;
  int lane = threadIdx.x & 63;
  uint2 rootv = *(const uint2*)(H + ((size_t)node<<8) + (lane<<2));
  agg_row(H, Aout + (size_t)el*NS + ((size_t)idx<<8), row_ptr, csr_src, node, lane);
  *(uint2*)(Rout + (size_t)el*NS + ((size_t)idx<<8) + (lane<<2)) = rootv;
}

// ---------------- dense GEMM, BK=64 ----------------
// Tile 128x128, K=512 as [A(256) | root(256)]. LDS As/Bs = [128][64] u16,
// rows 128B, 8 slots of 16B. Swizzle: LDS[row][slot] holds global piece
// slot ^ (row&7); store side via per-lane source piece p=(l&7)^(l>>3),
// read side via byte = row*128 + ((fkq*16 + kin*64) ^ ((row&7)<<4)).
// XOR applied to FULL offset (round-11 lesson).
__device__ __forceinline__ void gemm_bk64_body(
    const u16* __restrict__ aBase, const u16* __restrict__ rBase,
    const u16* __restrict__ wBase, const float* __restrict__ be,
    u16* __restrict__ Oe, int N, int relu_flag, u16* As, u16* Bs)
{
  int tid = threadIdx.x;
  int lane = tid & 63, w = tid >> 6;
  int wr = w >> 1, wc = w & 1;
  int m0 = blockIdx.x * 128;
  int n0 = blockIdx.y * 128;

  int lr8 = lane >> 3;               // 0..7
  int p   = (lane & 7) ^ lr8;        // per-lane source piece (16B units)
  long long asrc[4]; u16* aL[4];
  long long bsrc[4]; u16* bL[4];
  #pragma unroll
  for (int j=0;j<4;j++){
    int c = w*4 + j;                 // chunk 0..15 (1KB = 8 rows x 128B)
    int arow = m0 + c*8 + lr8; if (arow >= N) arow = N-1;
    asrc[j] = (long long)arow*256 + p*8;
    aL[j] = As + (size_t)c*512;
    int bcol = n0 + c*8 + lr8;       // < 256 always
    bsrc[j] = (long long)bcol*512 + p*8;
    bL[j] = Bs + (size_t)c*512;
  }

  f32x4 acc[4][4];
  #pragma unroll
  for (int a=0;a<4;a++)
    #pragma unroll
    for (int b=0;b<4;b++) acc[a][b] = (f32x4){0.f,0.f,0.f,0.f};

  int fr = lane & 15;
  int fkq = lane >> 4;               // 0..3 -> byte 16*fkq within 32-k window

  #pragma unroll 1
  for (int kk=0; kk<8; ++kk){
    const u16* sA = (kk < 4) ? aBase : rBase;
    int koff = (kk & 3) * 64;        // elems within the 256-k half
    #pragma unroll
    for (int j=0;j<4;j++){
      GLOAD_LDS16(sA + asrc[j] + koff, aL[j]);
      GLOAD_LDS16(wBase + bsrc[j] + kk*64, bL[j]);
    }
    __syncthreads();
    #pragma unroll
    for (int kin=0; kin<2; ++kin){
      unsigned fb = (unsigned)(fkq*16 + kin*64);
      s16x8 af[4], bf[4];
      #pragma unroll
      for (int mi=0;mi<4;mi++){
        int row = wr*64 + mi*16 + fr;
        unsigned byte = ((unsigned)row << 7) + (fb ^ (((unsigned)(row & 7)) << 4));
        af[mi] = *(const s16x8*)((const char*)As + byte);
      }
      #pragma unroll
      for (int ni=0;ni<4;ni++){
        int col = wc*64 + ni*16 + fr;
        unsigned byte = ((unsigned)col << 7) + (fb ^ (((unsigned)(col & 7)) << 4));
        bf[ni] = *(const s16x8*)((const char*)Bs + byte);
      }
      #pragma unroll
      for (int mi=0;mi<4;mi++)
        #pragma unroll
        for (int ni=0;ni<4;ni++)
          acc[mi][ni] = __builtin_amdgcn_mfma_f32_16x16x32_bf16(af[mi], bf[ni], acc[mi][ni], 0, 0, 0);
    }
    __syncthreads();
  }

  int fq = lane >> 4;
  #pragma unroll
  for (int ni=0;ni<4;ni++){
    int col = n0 + wc*64 + ni*16 + fr;
    float bv = be[col];
    #pragma unroll
    for (int mi=0;mi<4;mi++){
      int rowb = m0 + wr*64 + mi*16 + fq*4;
      f32x4 v = acc[mi][ni];
      #pragma unroll
      for (int j=0;j<4;j++){
        int row = rowb + j;
        if (row < N){
          float o = v[j] + bv;
          if (relu_flag) o = fmaxf(o, 0.f);
          Oe[(size_t)row*DH + col] = f2bf(o);
        }
      }
    }
  }
}

// layer-0: shared A0/bh, per-(group)expert W
__global__ __launch_bounds__(256,2) void gemm0g_k(
    const u16* __restrict__ A0, const u16* __restrict__ bh,
    const u16* __restrict__ WT, const float* __restrict__ bias,
    u16* __restrict__ Hout, int N){
  __shared__ u16 As[128*64];
  __shared__ u16 Bs[128*64];
  int el = blockIdx.z;
  gemm_bk64_body(A0, bh, WT + (size_t)el*(256*512), bias + el*256,
                 Hout + (size_t)el*((size_t)N*DH), N, 1, As, Bs);
}
// layer-1: per-expert A/H/W
__global__ __launch_bounds__(256,2) void gemm1g_k(
    const u16* __restrict__ Aagg, const u16* __restrict__ Hroot,
    const u16* __restrict__ WT, const float* __restrict__ bias,
    u16* __restrict__ Hout, int N){
  __shared__ u16 As[128*64];
  __shared__ u16 Bs[128*64];
  int el = blockIdx.z;
  size_t NS = (size_t)N*DH;
  gemm_bk64_body(Aagg + (size_t)el*NS, Hroot + (size_t)el*NS,
                 WT + (size_t)el*(256*512), bias + el*256,
                 Hout + (size_t)el*NS, N, 1, As, Bs);
}

// sparse layer-2 GEMM: compacted linear A and root (proven BK=32 body)
__global__ __launch_bounds__(256,2) void gemm2sg_k(
    const u16* __restrict__ Aagg, const u16* __restrict__ Rc,
    const u16* __restrict__ WT, const float* __restrict__ bias,
    u16* __restrict__ Hout, const int* __restrict__ cnte, int N, int gBase)
{
  __shared__ u16 As[128*32];
  __shared__ u16 Bs[128*32];
  int el = blockIdx.z;
  int cnt = cnte[gBase + el];
  int m0 = blockIdx.x * 128;
  if (m0 >= cnt) return;
  size_t NS = (size_t)N*DH;
  const u16* aBase = Aagg + (size_t)el*NS;
  const u16* rBase = Rc + (size_t)el*NS;
  const u16* wBase = WT + (size_t)el*(256*512);
  const float* be  = bias + el*256;
  u16* Oe = Hout + (size_t)el*NS;

  int tid = threadIdx.x;
  int lane = tid & 63, w = tid >> 6;
  int wr = w >> 1, wc = w & 1;
  int n0 = blockIdx.y * 128;

  int lrow = lane >> 2;
  int q8   = (((lane & 3) ^ ((lane >> 3) & 3))) * 8;
  int r0 = w*16 + lrow;
  int r1 = (w+4)*16 + lrow;
  int ai0 = m0 + r0; if (ai0 >= cnt) ai0 = cnt-1;
  int ai1 = m0 + r1; if (ai1 >= cnt) ai1 = cnt-1;
  long long aoff0 = (long long)ai0*256 + q8;
  long long aoff1 = (long long)ai1*256 + q8;
  long long boff0 = (long long)(n0 + r0)*512 + q8;
  long long boff1 = (long long)(n0 + r1)*512 + q8;
  u16* aL0 = As + (size_t)w*512;
  u16* aL1 = As + (size_t)(w+4)*512;
  u16* bL0 = Bs + (size_t)w*512;
  u16* bL1 = Bs + (size_t)(w+4)*512;

  f32x4 acc[4][4];
  #pragma unroll
  for (int a=0;a<4;a++)
    #pragma unroll
    for (int b=0;b<4;b++) acc[a][b] = (f32x4){0.f,0.f,0.f,0.f};

  int fr = lane & 15;
  int fk = (((lane >> 4) ^ ((fr >> 1) & 3))) * 8;
  const u16* aRead = As + (size_t)(wr*64 + fr)*32 + fk;
  const u16* bRead = Bs + (size_t)(wc*64 + fr)*32 + fk;

  #pragma unroll 1
  for (int half=0; half<2; ++half){
    const u16* sA = half ? rBase : aBase;
    #pragma unroll 1
    for (int kk=0; kk<8; ++kk){
      int kin = kk*32;
      int kg  = half*256 + kin;
      GLOAD_LDS16(sA + aoff0 + kin, aL0);
      GLOAD_LDS16(sA + aoff1 + kin, aL1);
      GLOAD_LDS16(wBase + boff0 + kg, bL0);
      GLOAD_LDS16(wBase + boff1 + kg, bL1);
      __syncthreads();
      s16x8 af[4], bf[4];
      #pragma unroll
      for (int mi=0;mi<4;mi++) af[mi] = *(const s16x8*)(aRead + mi*16*32);
      #pragma unroll
      for (int ni=0;ni<4;ni++) bf[ni] = *(const s16x8*)(bRead + ni*16*32);
      #pragma unroll
      for (int mi=0;mi<4;mi++)
        #pragma unroll
        for (int ni=0;ni<4;ni++)
          acc[mi][ni] = __builtin_amdgcn_mfma_f32_16x16x32_bf16(af[mi], bf[ni], acc[mi][ni], 0, 0, 0);
      __syncthreads();
    }
  }
  int fq = lane >> 4;
  #pragma unroll
  for (int ni=0;ni<4;ni++){
    int col = n0 + wc*64 + ni*16 + fr;
    float bv = be[col];
    #pragma unroll
    for (int mi=0;mi<4;mi++){
      int rowb = m0 + wr*64 + mi*16 + fq*4;
      f32x4 v = acc[mi][ni];
      #pragma unroll
      for (int j=0;j<4;j++){
        int row = rowb + j;
        if (row < cnt){
          float o = v[j] + bv;
          Oe[(size_t)row*DH + col] = f2bf(o);
        }
      }
    }
  }
}

// ---------------- combine (group-local sparse, write/accumulate) -----------
__global__ __launch_bounds__(256) void combine_spg_k(const u16* __restrict__ H3c,
    const int* __restrict__ ridx, const int* __restrict__ ppos,
    const float* __restrict__ rval, float* __restrict__ out,
    int N, int gBase, int ezCnt, int first){
  int n = blockIdx.x; if (n>=N) return;
  int f = threadIdx.x;
  size_t NS = (size_t)N*DH;
  size_t off = (size_t)n*DH + f;
  float acc = first ? 0.f : out[off];
  #pragma unroll
  for (int p=0;p<2;p++){
    int el = ridx[n*2+p] - gBase;
    if (el >= 0 && el < ezCnt)
      acc += rval[n*2+p] * bitsToF(((u32)H3c[(size_t)el*NS + (size_t)ppos[n*2+p]*DH + f])<<16);
  }
  out[off] = acc;
}

extern "C" void kernel_launch(void* const* d_in, const int* in_sizes, int n_in,
                              void* d_out, int out_size, void* d_ws, size_t ws_size,
                              hipStream_t stream)
{
  const float* x    = (const float*)d_in[0];
  const int*   ei   = (const int*)d_in[1];
  const int*   batch= (const int*)d_in[2];
  const float* encW = (const float*)d_in[3];
  const float* encb = (const float*)d_in[4];
  const float* rW1  = (const float*)d_in[5];
  const float* rb1  = (const float*)d_in[6];
  const float* rW2  = (const float*)d_in[7];
  const float* rb2  = (const float*)d_in[8];
  const float* Wrel = (const float*)d_in[9];
  const float* brel = (const float*)d_in[10];
  const float* Wroot= (const float*)d_in[11];
  int N = in_sizes[2];
  int E = in_sizes[1]/2;
  float* out = (float*)d_out;
  (void)n_in; (void)out_size;

  size_t NS = (size_t)N*DH;
  char* p = (char*)d_ws;
  auto carve = [&](size_t bytes)->char*{
    char* r = p; p += (bytes + 255) & ~(size_t)255; return r;
  };
  u16*  bh   = (u16*)carve(NS*2);
  u16*  WT   = (u16*)carve((size_t)3*NEXP*256*512*2);
  int*  deg  = (int*)carve((size_t)N*4 + 64*4);
  int*  ng   = deg + N;
  int*  eg   = ng + GNUM;
  int*  row_ptr = (int*)carve(((size_t)N+1)*4);
  int*  cursor  = (int*)carve((size_t)N*4);
  int*  csr     = (int*)carve((size_t)E*4);
  float* sizef  = (float*)carve(GNUM*2*4);
  int*  ridx    = (int*)carve((size_t)N*2*4);
  float* rvalv  = (float*)carve((size_t)N*2*4);
  int*  ecnt    = (int*)carve(NEXP*4);
  int*  plist   = (int*)carve((size_t)NEXP*N*4);
  int*  ppos    = (int*)carve((size_t)N*2*4);
  u16*  A0      = (u16*)carve(NS*2);
  size_t baseUsed = (size_t)(p - (char*)d_ws);

  int EZ = 0;
  for (int cand = NEXP; cand >= 1; cand >>= 1){
    if (baseUsed + (size_t)cand*3*NS*2 <= ws_size){ EZ = cand; break; }
  }
  if (EZ == 0){ mark_fail_k<<<1,1,0,stream>>>(out); return; }
  int ezShift = (EZ==8)?3 : (EZ==4)?2 : (EZ==2)?1 : 0;

  u16* Abuf = (u16*)carve((size_t)EZ*NS*2);   // dense A1 / compact A2
  u16* Hc   = (u16*)carve((size_t)EZ*NS*2);   // H1 / compact root
  u16* Hn   = (u16*)carve((size_t)EZ*NS*2);   // H2 / compact H3
  float* hf; float* rh;
  if (EZ >= 2){ hf = (float*)Abuf; rh = (float*)Hn; }
  else {
    hf = (float*)carve(NS*4);
    rh = (float*)carve(NS*4);
    if ((size_t)(p - (char*)d_ws) > ws_size){ mark_fail_k<<<1,1,0,stream>>>(out); return; }
  }

  hipMemsetAsync(deg, 0, (size_t)N*4 + (size_t)2*GNUM*4, stream);
  hipMemsetAsync(ecnt, 0, NEXP*4, stream);

  int eb = (E + 255)/256;
  count_edges_k<<<eb, 256, 0, stream>>>(ei, batch, deg, eg, E);
  count_nodes_k<<<(N+255)/256, 256, 0, stream>>>(batch, ng, N);
  scan_deg_k<<<1, SCAN_T, 0, stream>>>(deg, row_ptr, cursor, N);
  scatter_edges_k<<<eb, 256, 0, stream>>>(ei, cursor, csr, E);
  size_feats_k<<<1, 64, 0, stream>>>(ng, eg, sizef);
  encoder_k<<<N, 256, 0, stream>>>(x, encW, encb, hf, bh, N);
  convw_k<<<dim3(16,2,3*NEXP), dim3(64,4), 0, stream>>>(Wrel, Wroot, WT);
  router1_k<<<(N+R1N-1)/R1N, 256, 0, stream>>>(hf, sizef, batch, rW1, rb1, rh, N);
  router2_k<<<(N+3)/4, 256, 0, stream>>>(rh, rW2, rb2, ridx, rvalv, N);
  rsort_k<<<(N+255)/256, 256, 0, stream>>>(ridx, ecnt, plist, ppos, N);

  int aggx = (N+3)/4;
  int mt128 = (N+127)/128;
  const size_t WE = (size_t)256*512;

  agg0_k<<<aggx, 256, 0, stream>>>(bh, A0, row_ptr, csr, N);

  // split points for the layer-1 dense aggregate (multiple of 4 nodes)
  int half0 = (((N+1)/2) + 3) & ~3;
  if (half0 > N) half0 = N;
  int half1 = N - half0;
  int g1a = ((half0+3)/4)*EZ;
  int g1b = ((half1+3)/4)*EZ;

  for (int g = 0; g < NEXP; g += EZ){
    // layer 0 (dense BK64): shared A0/bh -> Hc (H1, relu)
    gemm0g_k<<<dim3(mt128,2,EZ), 256, 0, stream>>>(A0, bh,
        WT + ((size_t)0*NEXP + g)*WE, brel + (0*NEXP + g)*256, Hc, N);
    // layer 1 (dense): XCD-pinned aggregate Hc -> Abuf (two half dispatches)
    agg1a_k<<<g1a, 256, 0, stream>>>(Hc, Abuf, row_ptr, csr, N, 0, half0, EZ-1, ezShift);
    if (half1 > 0)
      agg1b_k<<<g1b, 256, 0, stream>>>(Hc, Abuf, row_ptr, csr, N, half0, half1, EZ-1, ezShift);
    // layer-1 GEMM (dense BK64) -> Hn (H2, relu)
    gemm1g_k<<<dim3(mt128,2,EZ), 256, 0, stream>>>(Abuf, Hc,
        WT + ((size_t)1*NEXP + g)*WE, brel + (1*NEXP + g)*256, Hn, N);
    // layer 2 (routing-sparse): compact agg Hn -> Abuf, root -> Hc (dead H1)
    agg2sg_k<<<dim3(aggx,EZ), 256, 0, stream>>>(Hn, Abuf, Hc, row_ptr, csr,
        plist, ecnt, N, g);
    gemm2sg_k<<<dim3(mt128,2,EZ), 256, 0, stream>>>(Abuf, Hc,
        WT + ((size_t)2*NEXP + g)*WE, brel + (2*NEXP + g)*256, Hn, ecnt, N, g);
    // routed combine (write on first group, accumulate after)
    combine_spg_k<<<N, 256, 0, stream>>>(Hn, ridx, ppos, rvalv, out, N, g, EZ, g==0);
  }
}